// Round 6
// baseline (1823.366 us; speedup 1.0000x reference)
//
#include <hip/hip_runtime.h>
#include <hip/hip_bf16.h>

#define GN 65536
#define GE 131072
#define GB 2048

typedef __attribute__((ext_vector_type(8))) short short8;
typedef __attribute__((ext_vector_type(4))) float floatx4;

static __device__ __forceinline__ float sigm(float x) { return 1.0f / (1.0f + __expf(-x)); }
static __device__ __forceinline__ float bf2f(unsigned short u) {
    union { unsigned int i; float f; } v; v.i = ((unsigned int)u) << 16; return v.f;
}
static __device__ __forceinline__ int geti(const void* p, long long i, int f64) {
    return f64 ? (int)((const long long*)p)[i] : ((const int*)p)[i];
}

// ---- batched per-tensor float dtype detector (one block per tensor) ----
struct DetectArgs { const void* src[17]; int nhalf[17]; int fi[17]; };
__global__ void k_dtype_all(DetectArgs a, int* __restrict__ flags) {
    const unsigned short* p = (const unsigned short*)a.src[blockIdx.x];
    const int n0 = a.nhalf[blockIdx.x];
    const int n = n0 < 16384 ? n0 : 16384;
    __shared__ unsigned int sAny[256], sOr[256];
    unsigned int any = 0, orEven = 0;
    for (int i = threadIdx.x; i < n; i += 256) {
        const unsigned short u = p[i];
        const float av = fabsf(bf2f(u));
        if (!(av <= 1e6f)) any = 1u;
        if ((i & 1) == 0) orEven |= u;
    }
    sAny[threadIdx.x] = any; sOr[threadIdx.x] = orEven;
    __syncthreads();
    for (int s = 128; s > 0; s >>= 1) {
        if (threadIdx.x < s) {
            sAny[threadIdx.x] |= sAny[threadIdx.x + s];
            sOr[threadIdx.x]  |= sOr[threadIdx.x + s];
        }
        __syncthreads();
    }
    if (threadIdx.x == 0) flags[a.fi[blockIdx.x]] = (sAny[0] || sOr[0] == 0u) ? 1 : 0;
}

// int64 detector, sampled
__global__ void k_i64(const unsigned int* __restrict__ p, long long nwords, int* __restrict__ flag) {
    const long long lim = nwords < 16384 ? nwords : 16384;
    __shared__ unsigned int s[256];
    unsigned int acc = 0;
    for (long long w = 1 + 2 * (long long)threadIdx.x; w < lim; w += 512) acc |= p[w];
    s[threadIdx.x] = acc;
    __syncthreads();
    for (int st = 128; st > 0; st >>= 1) {
        if (threadIdx.x < st) s[threadIdx.x] |= s[threadIdx.x + st];
        __syncthreads();
    }
    if (threadIdx.x == 0) *flag = (s[0] == 0u) ? 1 : 0;
}

// ---- batched f32 canonicalization of the 15 small float tensors ----
struct CvtArgs { const void* src[15]; float* dst[15]; int n[15]; int fi[15]; int pre[16]; };
__global__ void k_cvt_all(CvtArgs a, const int* __restrict__ flags) {
    const int b = blockIdx.x;
    int t = 0;
    while (t < 14 && b >= a.pre[t + 1]) ++t;
    const int i = (b - a.pre[t]) * 256 + threadIdx.x;
    if (i >= a.n[t]) return;
    const int f = flags[a.fi[t]];
    a.dst[t][i] = f ? ((const float*)a.src[t])[i] : bf2f(((const unsigned short*)a.src[t])[i]);
}

// repack w2 [128][4096] -> w2P bf16, COALESCED-FRAGMENT layout:
// group g = ((t*4 + kk)*8 + rb)  (t = col-tile of 128, kk = k-group of 32,
// rb = 16-row block), holding 512 elems: [lr*4+quad][8] with
// row = t*128 + rb*16 + lr, k = kk*32 + quad*8 + j.
// => each wave fragment load (fixed kk, rb) is one contiguous 1KB segment.
__global__ __launch_bounds__(256) void k_t2(const void* __restrict__ src,
                                            __hip_bfloat16* __restrict__ w2P,
                                            const int* __restrict__ flag) {
    const int tid8 = blockIdx.x * 256 + threadIdx.x;   // 65536 producers of 8 elems
    const int quad = tid8 & 3, lr = (tid8 >> 2) & 15, rb = (tid8 >> 6) & 7,
              kk = (tid8 >> 9) & 3, t = tid8 >> 11;
    const int n = t * 128 + rb * 16 + lr;              // output col 0..4095
    const int k0 = kk * 32 + quad * 8;                 // k 0..127
    const int isf32 = *flag;
    short8 v;
    #pragma unroll
    for (int j = 0; j < 8; ++j) {
        const size_t si = (size_t)(k0 + j) * 4096 + n;
        const float f = isf32 ? ((const float*)src)[si] : bf2f(((const unsigned short*)src)[si]);
        const __hip_bfloat16 b = __float2bfloat16(f);
        v[j] = *(const short*)&b;
    }
    *(short8*)(w2P + (size_t)tid8 * 8) = v;
}

// repack GRU weights: wpk[d][6][64]
__global__ void k_gpack(const float* __restrict__ w_ih, const float* __restrict__ w_hh,
                        float* __restrict__ wpk) {
    int idx = blockIdx.x * 256 + threadIdx.x;
    if (idx >= 64 * 384) return;
    const int d = idx / 384, rem = idx % 384, g = rem >> 6, k = rem & 63;
    wpk[idx] = (g < 3) ? w_ih[(g * 64 + d) * 64 + k] : w_hh[((g - 3) * 64 + d) * 64 + k];
}

__global__ void k_counts(const void* __restrict__ eidx, const int* __restrict__ fi64,
                         float* __restrict__ counts, int E_) {
    int e = blockIdx.x * 256 + threadIdx.x;
    if (e < E_) atomicAdd(&counts[geti(eidx, (long long)E_ + e, *fi64)], 1.0f);
}

__global__ void k_rowptr(const void* __restrict__ gi, const int* __restrict__ fi64,
                         int* __restrict__ rowptr, int N_, int B_) {
    int g = blockIdx.x * 256 + threadIdx.x;
    if (g > B_) return;
    const int f64 = *fi64;
    int lo = 0, hi = N_;
    while (lo < hi) { int mid = (lo + hi) >> 1; if (geti(gi, mid, f64) < g) lo = mid + 1; else hi = mid; }
    rowptr[g] = lo;
}

// lin0: out = relu(nf @ lin0_w + b)
__global__ __launch_bounds__(256) void k_lin0(const void* __restrict__ nf_raw,
                                              const float* __restrict__ w,
                                              const float* __restrict__ b,
                                              float* __restrict__ out,
                                              const int* __restrict__ flag) {
    const int ln = threadIdx.x >> 6;
    const int d = threadIdx.x & 63;
    const int n = blockIdx.x * 4 + ln;
    const int isf32 = *flag;
    __shared__ float s_nf[4][76];
    const size_t base = (size_t)n * 75;
    s_nf[ln][d] = isf32 ? ((const float*)nf_raw)[base + d] : bf2f(((const unsigned short*)nf_raw)[base + d]);
    if (d < 11) s_nf[ln][64 + d] = isf32 ? ((const float*)nf_raw)[base + 64 + d]
                                         : bf2f(((const unsigned short*)nf_raw)[base + 64 + d]);
    __syncthreads();
    float acc = b[d];
    #pragma unroll
    for (int i = 0; i < 75; ++i) acc += s_nf[ln][i] * w[i * 64 + d];
    out[(size_t)n * 64 + d] = fmaxf(acc, 0.0f);
}

// h1 = relu(ef @ w1 + b1) -> bf16, LINEAR layout [e][128]
__global__ __launch_bounds__(256) void k1_h1(const void* __restrict__ ef_raw,
                                             const float* __restrict__ w1,
                                             const float* __restrict__ b1,
                                             __hip_bfloat16* __restrict__ h1,
                                             const int* __restrict__ flag) {
    const int le = threadIdx.x >> 7;
    const int j = threadIdx.x & 127;
    const int e = blockIdx.x * 2 + le;
    const int isf32 = *flag;
    __shared__ float efs[2][16];
    if (j < 16) {
        const size_t idx = (size_t)e * 16 + j;
        efs[le][j] = isf32 ? ((const float*)ef_raw)[idx] : bf2f(((const unsigned short*)ef_raw)[idx]);
    }
    __syncthreads();
    float acc = b1[j];
    #pragma unroll
    for (int i = 0; i < 16; ++i) acc += efs[le][i] * w1[i * 128 + j];
    h1[(size_t)e * 128 + j] = __float2bfloat16(fmaxf(acc, 0.0f));
}

// FUSED NNConv v8: occupancy-targeted. 16 waves (1024 thr), each wave owns a
// 32x32 output sub-tile (af=32V, 4 named B buffers=32V, acc=16, msum=16 ->
// ~115 total regs => 4 waves/SIMD, vs r5's 180 => 2). B loads from L2-hot
// w2P at kk granularity, prefetch distance 2 kk-groups (~620cy at 4 w/SIMD),
// stable period-1 buffer rotation, all indices compile-time. Zero K-loop
// barriers; LDS only yT[64][129].
__global__ __launch_bounds__(1024, 4) void k23_fused(const __hip_bfloat16* __restrict__ h1,
                                                     const __hip_bfloat16* __restrict__ w2P,
                                                     const float* __restrict__ b2,
                                                     const float* __restrict__ out,
                                                     const void* __restrict__ eidx,
                                                     const int* __restrict__ fi64,
                                                     float* __restrict__ agg) {
    __shared__ float yT[64][129];
    const int tid = threadIdx.x;
    const int e0 = blockIdx.x * 128;
    const int f64 = *fi64;

    const int wave = tid >> 6, lane = tid & 63;
    const int wm = (wave >> 2) * 32;       // 4 M-slices of 32 rows
    const int wn4 = wave & 3;              // 4 N-slices of 32 cols
    const int wn = wn4 * 32;
    const int lr = lane & 15, quad = lane >> 4;

    // A fragments direct from global h1 (linear [e][128]): 8 loads, 32 VGPR
    short8 af[2][4];
    #pragma unroll
    for (int mt = 0; mt < 2; ++mt)
        #pragma unroll
        for (int kk = 0; kk < 4; ++kk)
            af[mt][kk] = *(const short8*)(h1 + (size_t)(e0 + wm + mt * 16 + lr) * 128
                                          + kk * 32 + quad * 8);

    // stage yT[d][e] = out[src[e]][d]  (8 threads per edge)
    {
        const int e = tid >> 3, d0 = (tid & 7) * 8;
        const int s = geti(eidx, e0 + e, f64);
        const float* srow = out + (size_t)s * 64 + d0;
        #pragma unroll
        for (int j = 0; j < 2; ++j) {
            float4 v = *(const float4*)(srow + j * 4);
            yT[d0 + j * 4 + 0][e] = v.x;
            yT[d0 + j * 4 + 1][e] = v.y;
            yT[d0 + j * 4 + 2][e] = v.z;
            yT[d0 + j * 4 + 3][e] = v.w;
        }
    }
    __syncthreads();                 // yT ready; the ONLY barrier

    const int lin = (lr * 4 + quad) * 8;   // lane offset inside a 512-elem group
    float msum[2][2][4] = {};

#define K23_LOAD(buf, tt, kk)                                                   \
    {                                                                           \
        _Pragma("unroll")                                                       \
        for (int nt = 0; nt < 2; ++nt) {                                        \
            const int g = ((tt) * 4 + (kk)) * 8 + wn4 * 2 + nt;                 \
            buf[nt] = *(const short8*)(w2P + (size_t)g * 512 + lin);            \
        }                                                                       \
    }

#define K23_MFMA(buf, kk)                                                       \
    {                                                                           \
        __builtin_amdgcn_s_setprio(1);                                          \
        _Pragma("unroll")                                                       \
        for (int mt = 0; mt < 2; ++mt) {                                        \
            acc[mt][0] = __builtin_amdgcn_mfma_f32_16x16x32_bf16(af[mt][kk], buf[0], acc[mt][0], 0, 0, 0); \
            acc[mt][1] = __builtin_amdgcn_mfma_f32_16x16x32_bf16(af[mt][kk], buf[1], acc[mt][1], 0, 0, 0); \
        }                                                                       \
        __builtin_amdgcn_s_setprio(0);                                          \
    }

    short8 b0[2], b1[2], b2r[2], b3[2];
    K23_LOAD(b0, 0, 0)
    K23_LOAD(b1, 0, 1)
    #pragma unroll 1
    for (int t = 0; t < 32; ++t) {
        const int n0 = t * 128;
        const int dcur = (n0 + wn) >> 6;
        const float b2v0 = b2[n0 + wn + lr];
        const float b2v1 = b2[n0 + wn + 16 + lr];
        float yv[2][4];
        #pragma unroll
        for (int mt = 0; mt < 2; ++mt)
            #pragma unroll
            for (int r = 0; r < 4; ++r)
                yv[mt][r] = yT[dcur][wm + mt * 16 + quad * 4 + r];

        floatx4 acc[2][2] = {};
        K23_LOAD(b2r, t, 2)
        K23_MFMA(b0, 0)
        K23_LOAD(b3, t, 3)
        K23_MFMA(b1, 1)
        if (t < 31) { K23_LOAD(b0, t + 1, 0) }
        K23_MFMA(b2r, 2)
        if (t < 31) { K23_LOAD(b1, t + 1, 1) }
        K23_MFMA(b3, 3)

        #pragma unroll
        for (int mt = 0; mt < 2; ++mt)
            #pragma unroll
            for (int r = 0; r < 4; ++r) {
                msum[mt][0][r] = fmaf(yv[mt][r], acc[mt][0][r] + b2v0, msum[mt][0][r]);
                msum[mt][1][r] = fmaf(yv[mt][r], acc[mt][1][r] + b2v1, msum[mt][1][r]);
            }
    }
#undef K23_LOAD
#undef K23_MFMA

    const int fbase = wn & 32;             // wn4 0,2 -> cols 0..31 (even d); 1,3 -> 32..63 (odd d)
    #pragma unroll
    for (int mt = 0; mt < 2; ++mt)
        #pragma unroll
        for (int r = 0; r < 4; ++r) {
            const int row = wm + mt * 16 + quad * 4 + r;
            const int dn = geti(eidx, (long long)GE + e0 + row, f64);
            #pragma unroll
            for (int nt = 0; nt < 2; ++nt)
                atomicAdd(&agg[(size_t)dn * 64 + fbase + nt * 16 + lr], msum[mt][nt][r]);
        }
}

// GRU v3 (r10-verified): block = 64 nodes, 4 waves split the d-loop
__global__ __launch_bounds__(256) void k4_gru(const float* __restrict__ agg,
                                              const float* __restrict__ counts,
                                              const float* __restrict__ cbias,
                                              const float* __restrict__ wpk,
                                              const float* __restrict__ b_ih,
                                              const float* __restrict__ b_hh,
                                              float* __restrict__ out) {
    const int wv = threadIdx.x >> 6;
    const int lane = threadIdx.x & 63;
    const int nb0 = blockIdx.x * 64;
    __shared__ float sM[64][65], sH[64][65];

    #pragma unroll 4
    for (int i = 0; i < 16; ++i) {
        const int r = i * 4 + wv;
        sM[r][lane] = agg[(size_t)(nb0 + r) * 64 + lane];
        sH[r][lane] = out[(size_t)(nb0 + r) * 64 + lane];
    }
    __syncthreads();
    const float rcnt = 1.0f / fmaxf(counts[nb0 + lane], 1.0f);
    float m[64], h[64];
    #pragma unroll
    for (int k = 0; k < 64; ++k) {
        m[k] = fmaxf(sM[lane][k] * rcnt + cbias[k], 0.0f);
        h[k] = sH[lane][k];
    }
    __syncthreads();

    const int d0 = wv * 16;
    #pragma unroll 1
    for (int dd = 0; dd < 16; ++dd) {
        const int d = d0 + dd;
        const float* wr = wpk + d * 384;
        float a0 = b_ih[d], a1 = b_ih[64 + d], a2 = b_ih[128 + d];
        float g0 = b_hh[d], g1 = b_hh[64 + d], g2 = b_hh[128 + d];
        #pragma unroll
        for (int k = 0; k < 64; ++k) {
            a0 = fmaf(m[k], wr[k], a0);
            a1 = fmaf(m[k], wr[64 + k], a1);
            a2 = fmaf(m[k], wr[128 + k], a2);
            g0 = fmaf(h[k], wr[192 + k], g0);
            g1 = fmaf(h[k], wr[256 + k], g1);
            g2 = fmaf(h[k], wr[320 + k], g2);
        }
        const float r_ = sigm(a0 + g0);
        const float z  = sigm(a1 + g1);
        const float nn = tanhf(a2 + r_ * g2);
        const float hd = sH[lane][d];
        sM[lane][d] = (1.0f - z) * nn + z * hd;
    }
    __syncthreads();
    #pragma unroll 4
    for (int i = 0; i < 16; ++i) {
        const int r = i * 4 + wv;
        out[(size_t)(nb0 + r) * 64 + lane] = sM[r][lane];
    }
}

// FUSED Set2Set: all 3 processing steps in ONE launch (per-graph state lives
// in LDS/registers; qstar written once at the end).
__global__ __launch_bounds__(256) void k5_fused(float* __restrict__ qstar,
                                                const float* __restrict__ w_ih,
                                                const float* __restrict__ w_hh,
                                                const float* __restrict__ b_ih,
                                                const float* __restrict__ b_hh,
                                                const float* __restrict__ out,
                                                const int* __restrict__ rowptr) {
    const int g = blockIdx.x;
    const int j = threadIdx.x;
    __shared__ float qs[128], hv[64], gates[256];
    __shared__ float smw[4], sSw[4], srw[4][64];
    if (j < 128) qs[j] = 0.0f;
    if (j < 64) hv[j] = 0.0f;
    float creg = 0.0f;               // cs state (threads j<64)
    const int wv = j >> 6, lane = j & 63;
    const int start = rowptr[g], end = rowptr[g + 1];
    const float bsum = b_ih[j] + b_hh[j];

    for (int step = 0; step < 3; ++step) {
        __syncthreads();             // qs/hv (and smw/srw reuse) ready
        float acc = bsum;
        for (int k4 = 0; k4 < 128; k4 += 4) {
            float4 v = *(const float4*)(w_ih + (size_t)j * 128 + k4);
            const float* pv = (const float*)&v;
            #pragma unroll
            for (int t = 0; t < 4; ++t) acc += qs[k4 + t] * pv[t];
        }
        for (int k4 = 0; k4 < 64; k4 += 4) {
            float4 v = *(const float4*)(w_hh + (size_t)j * 64 + k4);
            const float* pv = (const float*)&v;
            #pragma unroll
            for (int t = 0; t < 4; ++t) acc += hv[k4 + t] * pv[t];
        }
        gates[j] = acc;
        __syncthreads();
        if (j < 64) {
            const float ig = sigm(gates[j]);
            const float fg = sigm(gates[64 + j]);
            const float gg = tanhf(gates[128 + j]);
            const float og = sigm(gates[192 + j]);
            creg = fg * creg + ig * gg;
            const float h = og * tanhf(creg);
            hv[j] = h;
            qs[j] = h;
        }
        __syncthreads();
        // attention: wave wv handles nodes start+wv, start+wv+4, ...
        const float q = hv[lane];
        float m = -3.4e38f, S = 0.0f, racc = 0.0f;
        for (int n = start + wv; n < end; n += 4) {
            const float ov = out[(size_t)n * 64 + lane];
            float p = ov * q;
            #pragma unroll
            for (int off = 1; off < 64; off <<= 1) p += __shfl_xor(p, off);
            if (p > m) {
                const float sc = __expf(m - p);
                S = S * sc + 1.0f;
                racc = racc * sc + ov;
                m = p;
            } else {
                const float w = __expf(p - m);
                S += w;
                racc += w * ov;
            }
        }
        if (lane == 0) { smw[wv] = m; sSw[wv] = S; }
        srw[wv][lane] = racc;
        __syncthreads();
        if (wv == 0) {
            const float mstar = fmaxf(fmaxf(smw[0], smw[1]), fmaxf(smw[2], smw[3]));
            float Ssum = 0.0f, rsum = 0.0f;
            #pragma unroll
            for (int i = 0; i < 4; ++i) {
                const float sc = __expf(smw[i] - mstar);   // empty wave: exp(-huge)=0
                Ssum += sSw[i] * sc;
                rsum += srw[i][lane] * sc;
            }
            qs[64 + lane] = rsum / (Ssum + 1e-16f);
        }
    }
    __syncthreads();
    if (j < 128) qstar[(size_t)g * 128 + j] = qs[j];
}

__global__ void k_out(const float* __restrict__ qstar, const float* __restrict__ outb,
                      float* __restrict__ dst, int nq, int nfeat, int out_n) {
    int i = blockIdx.x * 256 + threadIdx.x;
    if (i >= out_n) return;
    float v = 0.0f;
    if (i < nq) v = qstar[i];
    else if (i - nq < nfeat) v = outb[i - nq];
    dst[i] = v;
}

extern "C" void kernel_launch(void* const* d_in, const int* in_sizes, int n_in,
                              void* d_out, int out_size, void* d_ws, size_t ws_size,
                              hipStream_t stream) {
    constexpr int N = GN, E = GE, B = GB;

    char* ws = (char*)d_ws;
    size_t off = 0;
    auto alloc = [&](size_t bytes) { size_t o = off; off = (off + bytes + 255) & ~(size_t)255; return o; };

    int*   fl     = (int*)  (ws + alloc(19 * 4));
    int*   flagE  = (int*)  (ws + alloc(256));
    int*   flagG  = (int*)  (ws + alloc(256));
    float* counts = (float*)(ws + alloc((size_t)N * 4));
    int*   rowptr = (int*)  (ws + alloc((size_t)(B + 1) * 4));
    float* outbuf = (float*)(ws + alloc((size_t)N * 64 * 4));
    float* agg    = (float*)(ws + alloc((size_t)N * 64 * 4));
    float* qstar  = (float*)(ws + alloc((size_t)B * 128 * 4));
    __hip_bfloat16* h1  = (__hip_bfloat16*)(ws + alloc((size_t)E * 128 * 2));
    __hip_bfloat16* w2P = (__hip_bfloat16*)(ws + alloc((size_t)4096 * 128 * 2));
    float* wpk    = (float*)(ws + alloc((size_t)64 * 384 * 4));

    const int fidx[15]  = {4, 5, 6, 7, 8, 9, 10, 11, 12, 13, 14, 15, 16, 17, 18};
    const int fsize[15] = {75 * 64, 64, 16 * 128, 128, 128 * 4096, 4096, 64,
                           192 * 64, 192 * 64, 192, 192, 256 * 128, 256 * 64, 256, 256};
    float* F[19] = {};
    for (int t = 0; t < 15; ++t) F[fidx[t]] = (float*)(ws + alloc((size_t)fsize[t] * 4));

    DetectArgs da;
    da.src[0] = d_in[0]; da.nhalf[0] = N * 75; da.fi[0] = 0;
    da.src[1] = d_in[1]; da.nhalf[1] = E * 16; da.fi[1] = 1;
    for (int t = 0; t < 15; ++t) { da.src[2 + t] = d_in[fidx[t]]; da.nhalf[2 + t] = fsize[t]; da.fi[2 + t] = fidx[t]; }
    k_dtype_all<<<17, 256, 0, stream>>>(da, fl);
    k_i64<<<1, 256, 0, stream>>>((const unsigned int*)d_in[2], (long long)2 * E, flagE);
    k_i64<<<1, 256, 0, stream>>>((const unsigned int*)d_in[3], (long long)N, flagG);

    CvtArgs ca;
    int pre = 0;
    for (int t = 0; t < 15; ++t) {
        ca.src[t] = d_in[fidx[t]]; ca.dst[t] = F[fidx[t]]; ca.n[t] = fsize[t]; ca.fi[t] = fidx[t];
        ca.pre[t] = pre; pre += (fsize[t] + 255) / 256;
    }
    ca.pre[15] = pre;
    k_cvt_all<<<pre, 256, 0, stream>>>(ca, fl);
    k_t2<<<256, 256, 0, stream>>>(d_in[8], w2P, fl + 8);
    k_gpack<<<(64 * 384 + 255) / 256, 256, 0, stream>>>(F[11], F[12], wpk);

    hipMemsetAsync(counts, 0, (size_t)N * 4, stream);
    hipMemsetAsync(qstar, 0, (size_t)B * 128 * 4, stream);

    k_counts<<<E / 256, 256, 0, stream>>>(d_in[2], flagE, counts, E);
    k_rowptr<<<(B + 1 + 255) / 256, 256, 0, stream>>>(d_in[3], flagG, rowptr, N, B);
    k_lin0<<<N / 4, 256, 0, stream>>>(d_in[0], F[4], F[5], outbuf, fl + 0);
    k1_h1<<<E / 2, 256, 0, stream>>>(d_in[1], F[6], F[7], h1, fl + 1);

    for (int it = 0; it < 3; ++it) {
        hipMemsetAsync(agg, 0, (size_t)N * 64 * 4, stream);
        k23_fused<<<E / 128, 1024, 0, stream>>>(h1, w2P, F[9], outbuf, d_in[2], flagE, agg);
        k4_gru<<<N / 64, 256, 0, stream>>>(agg, counts, F[10], wpk, F[13], F[14], outbuf);
    }
    k5_fused<<<B, 256, 0, stream>>>(qstar, F[15], F[16], F[17], F[18], outbuf, rowptr);
    k_out<<<(out_size + 255) / 256, 256, 0, stream>>>(qstar, outbuf, (float*)d_out,
                                                      B * 128, N * 64, out_size);
}

// Round 7
// 1060.333 us; speedup vs baseline: 1.7196x; 1.7196x over previous
//
#include <hip/hip_runtime.h>
#include <hip/hip_bf16.h>

#define GN 65536
#define GE 131072
#define GB 2048

typedef __attribute__((ext_vector_type(8))) short short8;
typedef __attribute__((ext_vector_type(4))) float floatx4;

static __device__ __forceinline__ float sigm(float x) { return 1.0f / (1.0f + __expf(-x)); }
static __device__ __forceinline__ float bf2f(unsigned short u) {
    union { unsigned int i; float f; } v; v.i = ((unsigned int)u) << 16; return v.f;
}
static __device__ __forceinline__ int geti(const void* p, long long i, int f64) {
    return f64 ? (int)((const long long*)p)[i] : ((const int*)p)[i];
}

// ---- merged detectors: blocks 0-16 float-dtype, 17 edge-i64, 18 graph-i64 ----
struct DetectArgs { const void* src[17]; int nhalf[17]; int fi[17]; };
__global__ void k_detect(DetectArgs a, const unsigned int* __restrict__ pe,
                         const unsigned int* __restrict__ pg,
                         int* __restrict__ flags, int* __restrict__ flagE,
                         int* __restrict__ flagG) {
    __shared__ unsigned int sA[256], sB[256];
    if (blockIdx.x >= 17) {
        const unsigned int* p = (blockIdx.x == 17) ? pe : pg;
        const long long nwords = (blockIdx.x == 17) ? (long long)2 * GE : (long long)GN;
        const long long lim = nwords < 16384 ? nwords : 16384;
        unsigned int acc = 0;
        for (long long w = 1 + 2 * (long long)threadIdx.x; w < lim; w += 512) acc |= p[w];
        sA[threadIdx.x] = acc;
        __syncthreads();
        for (int st = 128; st > 0; st >>= 1) {
            if (threadIdx.x < st) sA[threadIdx.x] |= sA[threadIdx.x + st];
            __syncthreads();
        }
        if (threadIdx.x == 0) *((blockIdx.x == 17) ? flagE : flagG) = (sA[0] == 0u) ? 1 : 0;
        return;
    }
    const unsigned short* p = (const unsigned short*)a.src[blockIdx.x];
    const int n0 = a.nhalf[blockIdx.x];
    const int n = n0 < 16384 ? n0 : 16384;
    unsigned int any = 0, orEven = 0;
    for (int i = threadIdx.x; i < n; i += 256) {
        const unsigned short u = p[i];
        const float av = fabsf(bf2f(u));
        if (!(av <= 1e6f)) any = 1u;
        if ((i & 1) == 0) orEven |= u;
    }
    sA[threadIdx.x] = any; sB[threadIdx.x] = orEven;
    __syncthreads();
    for (int s = 128; s > 0; s >>= 1) {
        if (threadIdx.x < s) {
            sA[threadIdx.x] |= sA[threadIdx.x + s];
            sB[threadIdx.x] |= sB[threadIdx.x + s];
        }
        __syncthreads();
    }
    if (threadIdx.x == 0) flags[a.fi[blockIdx.x]] = (sA[0] || sB[0] == 0u) ? 1 : 0;
}

// ---- batched f32 canonicalization of the 15 small float tensors ----
struct CvtArgs { const void* src[15]; float* dst[15]; int n[15]; int fi[15]; int pre[16]; };
__global__ void k_cvt_all(CvtArgs a, const int* __restrict__ flags) {
    const int b = blockIdx.x;
    int t = 0;
    while (t < 14 && b >= a.pre[t + 1]) ++t;
    const int i = (b - a.pre[t]) * 256 + threadIdx.x;
    if (i >= a.n[t]) return;
    const int f = flags[a.fi[t]];
    a.dst[t][i] = f ? ((const float*)a.src[t])[i] : bf2f(((const unsigned short*)a.src[t])[i]);
}

// repack w2 [128][4096] -> w2P bf16, COALESCED-FRAGMENT layout:
// group g = ((t*4 + kk)*8 + rb); each wave fragment load is one contiguous 1KB segment.
__global__ __launch_bounds__(256) void k_t2(const void* __restrict__ src,
                                            __hip_bfloat16* __restrict__ w2P,
                                            const int* __restrict__ flag) {
    const int tid8 = blockIdx.x * 256 + threadIdx.x;   // 65536 producers of 8 elems
    const int quad = tid8 & 3, lr = (tid8 >> 2) & 15, rb = (tid8 >> 6) & 7,
              kk = (tid8 >> 9) & 3, t = tid8 >> 11;
    const int n = t * 128 + rb * 16 + lr;              // output col 0..4095
    const int k0 = kk * 32 + quad * 8;                 // k 0..127
    const int isf32 = *flag;
    short8 v;
    #pragma unroll
    for (int j = 0; j < 8; ++j) {
        const size_t si = (size_t)(k0 + j) * 4096 + n;
        const float f = isf32 ? ((const float*)src)[si] : bf2f(((const unsigned short*)src)[si]);
        const __hip_bfloat16 b = __float2bfloat16(f);
        v[j] = *(const short*)&b;
    }
    *(short8*)(w2P + (size_t)tid8 * 8) = v;
}

// pack GRU weights into MFMA B-fragment layout, hi/lo bf16 split.
// seg(mat,nb,kk,part) = ((mat*12+nb)*2+kk)*2+part, 512 bf16 per seg:
// lane L slot: value = W[mat][c = nb*16 + (L&15)][k = kk*32 + (L>>4)*8 + j]
__global__ void k_gpack2(const float* __restrict__ w_ih, const float* __restrict__ w_hh,
                         __hip_bfloat16* __restrict__ gwp) {
    const int t = blockIdx.x * 256 + threadIdx.x;
    if (t >= 3072) return;
    const int lane = t & 63;
    const int kk = (t >> 6) & 1;
    const int nb = (t >> 7) % 12;
    const int mat = t / 1536;
    const float* W = mat ? w_hh : w_ih;          // [192][64]
    const int c = nb * 16 + (lane & 15);
    const int k0 = kk * 32 + (lane >> 4) * 8;
    short8 hi, lo;
    #pragma unroll
    for (int j = 0; j < 8; ++j) {
        const float v = W[c * 64 + k0 + j];
        const __hip_bfloat16 bh = __float2bfloat16(v);
        hi[j] = *(const short*)&bh;
        const __hip_bfloat16 bl = __float2bfloat16(v - __bfloat162float(bh));
        lo[j] = *(const short*)&bl;
    }
    const size_t base = (size_t)(((mat * 12 + nb) * 2 + kk) * 2);
    *(short8*)(gwp + (base + 0) * 512 + lane * 8) = hi;
    *(short8*)(gwp + (base + 1) * 512 + lane * 8) = lo;
}

__global__ void k_counts(const void* __restrict__ eidx, const int* __restrict__ fi64,
                         float* __restrict__ counts, int E_) {
    int e = blockIdx.x * 256 + threadIdx.x;
    if (e < E_) atomicAdd(&counts[geti(eidx, (long long)E_ + e, *fi64)], 1.0f);
}

__global__ void k_rowptr(const void* __restrict__ gi, const int* __restrict__ fi64,
                         int* __restrict__ rowptr, int N_, int B_) {
    int g = blockIdx.x * 256 + threadIdx.x;
    if (g > B_) return;
    const int f64 = *fi64;
    int lo = 0, hi = N_;
    while (lo < hi) { int mid = (lo + hi) >> 1; if (geti(gi, mid, f64) < g) lo = mid + 1; else hi = mid; }
    rowptr[g] = lo;
}

// lin0: out = relu(nf @ lin0_w + b)
__global__ __launch_bounds__(256) void k_lin0(const void* __restrict__ nf_raw,
                                              const float* __restrict__ w,
                                              const float* __restrict__ b,
                                              float* __restrict__ out,
                                              const int* __restrict__ flag) {
    const int ln = threadIdx.x >> 6;
    const int d = threadIdx.x & 63;
    const int n = blockIdx.x * 4 + ln;
    const int isf32 = *flag;
    __shared__ float s_nf[4][76];
    const size_t base = (size_t)n * 75;
    s_nf[ln][d] = isf32 ? ((const float*)nf_raw)[base + d] : bf2f(((const unsigned short*)nf_raw)[base + d]);
    if (d < 11) s_nf[ln][64 + d] = isf32 ? ((const float*)nf_raw)[base + 64 + d]
                                         : bf2f(((const unsigned short*)nf_raw)[base + 64 + d]);
    __syncthreads();
    float acc = b[d];
    #pragma unroll
    for (int i = 0; i < 75; ++i) acc += s_nf[ln][i] * w[i * 64 + d];
    out[(size_t)n * 64 + d] = fmaxf(acc, 0.0f);
}

// h1 = relu(ef @ w1 + b1) -> bf16, LINEAR layout [e][128]
__global__ __launch_bounds__(256) void k1_h1(const void* __restrict__ ef_raw,
                                             const float* __restrict__ w1,
                                             const float* __restrict__ b1,
                                             __hip_bfloat16* __restrict__ h1,
                                             const int* __restrict__ flag) {
    const int le = threadIdx.x >> 7;
    const int j = threadIdx.x & 127;
    const int e = blockIdx.x * 2 + le;
    const int isf32 = *flag;
    __shared__ float efs[2][16];
    if (j < 16) {
        const size_t idx = (size_t)e * 16 + j;
        efs[le][j] = isf32 ? ((const float*)ef_raw)[idx] : bf2f(((const unsigned short*)ef_raw)[idx]);
    }
    __syncthreads();
    float acc = b1[j];
    #pragma unroll
    for (int i = 0; i < 16; ++i) acc += efs[le][i] * w1[i * 128 + j];
    h1[(size_t)e * 128 + j] = __float2bfloat16(fmaxf(acc, 0.0f));
}

// FUSED NNConv (r5 best-measured version, 212us): B fragments from L2-resident
// w2P straight to NAMED double-buffered registers, t-loop hand-unrolled x2.
// Zero barriers in the K-loop; LDS only yT[64][129].
__global__ __launch_bounds__(512) void k23_fused(const __hip_bfloat16* __restrict__ h1,
                                                 const __hip_bfloat16* __restrict__ w2P,
                                                 const float* __restrict__ b2,
                                                 const float* __restrict__ out,
                                                 const void* __restrict__ eidx,
                                                 const int* __restrict__ fi64,
                                                 float* __restrict__ agg) {
    __shared__ float yT[64][129];
    const int tid = threadIdx.x;
    const int e0 = blockIdx.x * 128;
    const int f64 = *fi64;

    const int wave = tid >> 6, lane = tid & 63;
    const int wm = (wave >> 2) * 64;       // 2 M-slices of 64 rows
    const int wn = (wave & 3) * 32;        // 4 N-slices of 32 cols
    const int lr = lane & 15, quad = lane >> 4;

    // A fragments direct from global h1 (linear [e][128])
    short8 af[4][4];
    #pragma unroll
    for (int mt = 0; mt < 4; ++mt)
        #pragma unroll
        for (int kk = 0; kk < 4; ++kk)
            af[mt][kk] = *(const short8*)(h1 + (size_t)(e0 + wm + mt * 16 + lr) * 128
                                          + kk * 32 + quad * 8);

    // stage yT[d][e] = out[src[e]][d]
    {
        const int e = tid >> 2, d0 = (tid & 3) * 16;
        const int s = geti(eidx, e0 + e, f64);
        const float* srow = out + (size_t)s * 64 + d0;
        #pragma unroll
        for (int j = 0; j < 4; ++j) {
            float4 v = *(const float4*)(srow + j * 4);
            yT[d0 + j * 4 + 0][e] = v.x;
            yT[d0 + j * 4 + 1][e] = v.y;
            yT[d0 + j * 4 + 2][e] = v.z;
            yT[d0 + j * 4 + 3][e] = v.w;
        }
    }
    __syncthreads();                 // yT ready; the ONLY barrier

    const int lin = (lr * 4 + quad) * 8;   // lane offset inside a 512-elem group
    float msum[4][2][4] = {};

#define K23_LOADB(dst, tt)                                                      \
    _Pragma("unroll")                                                           \
    for (int kk = 0; kk < 4; ++kk) {                                            \
        _Pragma("unroll")                                                       \
        for (int nt = 0; nt < 2; ++nt) {                                        \
            const int g = ((tt) * 4 + kk) * 8 + (wn >> 4) + nt;                 \
            dst[kk][nt] = *(const short8*)(w2P + (size_t)g * 512 + lin);        \
        }                                                                       \
    }

#define K23_BODY(tt, buf) {                                                     \
    const int n0 = (tt) * 128;                                                  \
    const int dcur = (n0 + wn) >> 6;                                            \
    const float b2v0 = b2[n0 + wn + lr];                                        \
    const float b2v1 = b2[n0 + wn + 16 + lr];                                   \
    floatx4 acc[4][2] = {};                                                     \
    _Pragma("unroll")                                                           \
    for (int kk = 0; kk < 4; ++kk) {                                            \
        __builtin_amdgcn_s_setprio(1);                                          \
        _Pragma("unroll")                                                       \
        for (int mt = 0; mt < 4; ++mt) {                                        \
            acc[mt][0] = __builtin_amdgcn_mfma_f32_16x16x32_bf16(af[mt][kk], buf[kk][0], acc[mt][0], 0, 0, 0); \
            acc[mt][1] = __builtin_amdgcn_mfma_f32_16x16x32_bf16(af[mt][kk], buf[kk][1], acc[mt][1], 0, 0, 0); \
        }                                                                       \
        __builtin_amdgcn_s_setprio(0);                                          \
    }                                                                           \
    _Pragma("unroll")                                                           \
    for (int mt = 0; mt < 4; ++mt) {                                            \
        _Pragma("unroll")                                                       \
        for (int r = 0; r < 4; ++r) {                                           \
            const float yv = yT[dcur][wm + mt * 16 + quad * 4 + r];             \
            msum[mt][0][r] = fmaf(yv, acc[mt][0][r] + b2v0, msum[mt][0][r]);    \
            msum[mt][1][r] = fmaf(yv, acc[mt][1][r] + b2v1, msum[mt][1][r]);    \
        }                                                                       \
    }                                                                           \
}

    short8 bA[4][2], bB[4][2];
    K23_LOADB(bA, 0)
    #pragma unroll 1
    for (int t = 0; t < 32; t += 2) {
        K23_LOADB(bB, t + 1)          // in flight across BODY(t)
        K23_BODY(t, bA)
        if (t + 2 < 32) { K23_LOADB(bA, t + 2) }  // in flight across BODY(t+1)
        K23_BODY(t + 1, bB)
    }
#undef K23_LOADB
#undef K23_BODY

    const int fbase = (wn & 32);
    #pragma unroll
    for (int mt = 0; mt < 4; ++mt)
        #pragma unroll
        for (int r = 0; r < 4; ++r) {
            const int row = wm + mt * 16 + quad * 4 + r;
            const int dn = geti(eidx, (long long)GE + e0 + row, f64);
            #pragma unroll
            for (int nt = 0; nt < 2; ++nt)
                atomicAdd(&agg[(size_t)dn * 64 + fbase + nt * 16 + lr], msum[mt][nt][r]);
        }
}

// GRU v4: MFMA gate GEMMs. A = [m|h] bf16 (one rounding, gate err ~5e-4),
// weights hi/lo-split bf16 (exact to 2^-17) in B-fragment layout (gwp).
// Per wave: 16 nodes x 192 gates x K=64 -> 96 MFMA. Fused m-prologue +
// GRU nonlinearity epilogue on the verified C/D map (col=lane&15, row=quad*4+r).
__global__ __launch_bounds__(256) void k4_gru(const float* __restrict__ agg,
                                              const float* __restrict__ counts,
                                              const float* __restrict__ cbias,
                                              const __hip_bfloat16* __restrict__ gwp,
                                              const float* __restrict__ b_ih,
                                              const float* __restrict__ b_hh,
                                              float* __restrict__ out) {
    const int wv = threadIdx.x >> 6, lane = threadIdx.x & 63;
    const int lr = lane & 15, quad = lane >> 4;
    const int wnb0 = blockIdx.x * 64 + wv * 16;
    const int node = wnb0 + lr;

    const float rcnt = 1.0f / fmaxf(counts[node], 1.0f);
    const float* ap = agg + (size_t)node * 64;
    const float* hp = out + (size_t)node * 64;
    short8 am[2], ah[2];
    #pragma unroll
    for (int kk = 0; kk < 2; ++kk) {
        const int k0 = kk * 32 + quad * 8;
        #pragma unroll
        for (int j = 0; j < 8; ++j) {
            const float mv = fmaxf(ap[k0 + j] * rcnt + cbias[k0 + j], 0.0f);
            const __hip_bfloat16 mb = __float2bfloat16(mv);
            am[kk][j] = *(const short*)&mb;
            const __hip_bfloat16 hb = __float2bfloat16(hp[k0 + j]);
            ah[kk][j] = *(const short*)&hb;
        }
    }

    floatx4 ai[12] = {}, ahh[12] = {};
    #pragma unroll
    for (int nb = 0; nb < 12; ++nb) {
        #pragma unroll
        for (int kk = 0; kk < 2; ++kk) {
            #pragma unroll
            for (int part = 0; part < 2; ++part) {
                const short8 bi = *(const short8*)(gwp + (size_t)(((0 * 12 + nb) * 2 + kk) * 2 + part) * 512 + lane * 8);
                ai[nb] = __builtin_amdgcn_mfma_f32_16x16x32_bf16(am[kk], bi, ai[nb], 0, 0, 0);
                const short8 bh = *(const short8*)(gwp + (size_t)(((1 * 12 + nb) * 2 + kk) * 2 + part) * 512 + lane * 8);
                ahh[nb] = __builtin_amdgcn_mfma_f32_16x16x32_bf16(ah[kk], bh, ahh[nb], 0, 0, 0);
            }
        }
    }

    #pragma unroll
    for (int f = 0; f < 4; ++f) {
        const int d = f * 16 + lr;
        const float bir = b_ih[d],       bhr = b_hh[d];
        const float biz = b_ih[64 + d],  bhz = b_hh[64 + d];
        const float bin = b_ih[128 + d], bhn = b_hh[128 + d];
        #pragma unroll
        for (int r = 0; r < 4; ++r) {
            const int row = wnb0 + quad * 4 + r;
            const float rr = sigm(ai[f][r] + bir + ahh[f][r] + bhr);
            const float zz = sigm(ai[f + 4][r] + biz + ahh[f + 4][r] + bhz);
            const float nn = tanhf(ai[f + 8][r] + bin + rr * (ahh[f + 8][r] + bhn));
            const float hd = out[(size_t)row * 64 + d];
            out[(size_t)row * 64 + d] = (1.0f - zz) * nn + zz * hd;
        }
    }
}

// FUSED Set2Set: all 3 processing steps in ONE launch.
__global__ __launch_bounds__(256) void k5_fused(float* __restrict__ qstar,
                                                const float* __restrict__ w_ih,
                                                const float* __restrict__ w_hh,
                                                const float* __restrict__ b_ih,
                                                const float* __restrict__ b_hh,
                                                const float* __restrict__ out,
                                                const int* __restrict__ rowptr) {
    const int g = blockIdx.x;
    const int j = threadIdx.x;
    __shared__ float qs[128], hv[64], gates[256];
    __shared__ float smw[4], sSw[4], srw[4][64];
    if (j < 128) qs[j] = 0.0f;
    if (j < 64) hv[j] = 0.0f;
    float creg = 0.0f;               // cs state (threads j<64)
    const int wv = j >> 6, lane = j & 63;
    const int start = rowptr[g], end = rowptr[g + 1];
    const float bsum = b_ih[j] + b_hh[j];

    for (int step = 0; step < 3; ++step) {
        __syncthreads();             // qs/hv (and smw/srw reuse) ready
        float acc = bsum;
        for (int k4 = 0; k4 < 128; k4 += 4) {
            float4 v = *(const float4*)(w_ih + (size_t)j * 128 + k4);
            const float* pv = (const float*)&v;
            #pragma unroll
            for (int t = 0; t < 4; ++t) acc += qs[k4 + t] * pv[t];
        }
        for (int k4 = 0; k4 < 64; k4 += 4) {
            float4 v = *(const float4*)(w_hh + (size_t)j * 64 + k4);
            const float* pv = (const float*)&v;
            #pragma unroll
            for (int t = 0; t < 4; ++t) acc += hv[k4 + t] * pv[t];
        }
        gates[j] = acc;
        __syncthreads();
        if (j < 64) {
            const float ig = sigm(gates[j]);
            const float fg = sigm(gates[64 + j]);
            const float gg = tanhf(gates[128 + j]);
            const float og = sigm(gates[192 + j]);
            creg = fg * creg + ig * gg;
            const float h = og * tanhf(creg);
            hv[j] = h;
            qs[j] = h;
        }
        __syncthreads();
        // attention: wave wv handles nodes start+wv, start+wv+4, ...
        const float q = hv[lane];
        float m = -3.4e38f, S = 0.0f, racc = 0.0f;
        for (int n = start + wv; n < end; n += 4) {
            const float ov = out[(size_t)n * 64 + lane];
            float p = ov * q;
            #pragma unroll
            for (int off = 1; off < 64; off <<= 1) p += __shfl_xor(p, off);
            if (p > m) {
                const float sc = __expf(m - p);
                S = S * sc + 1.0f;
                racc = racc * sc + ov;
                m = p;
            } else {
                const float w = __expf(p - m);
                S += w;
                racc += w * ov;
            }
        }
        if (lane == 0) { smw[wv] = m; sSw[wv] = S; }
        srw[wv][lane] = racc;
        __syncthreads();
        if (wv == 0) {
            const float mstar = fmaxf(fmaxf(smw[0], smw[1]), fmaxf(smw[2], smw[3]));
            float Ssum = 0.0f, rsum = 0.0f;
            #pragma unroll
            for (int i = 0; i < 4; ++i) {
                const float sc = __expf(smw[i] - mstar);   // empty wave: exp(-huge)=0
                Ssum += sSw[i] * sc;
                rsum += srw[i][lane] * sc;
            }
            qs[64 + lane] = rsum / (Ssum + 1e-16f);
        }
    }
    __syncthreads();
    if (j < 128) qstar[(size_t)g * 128 + j] = qs[j];
}

__global__ void k_out(const float* __restrict__ qstar, const float* __restrict__ outb,
                      float* __restrict__ dst, int nq, int nfeat, int out_n) {
    int i = blockIdx.x * 256 + threadIdx.x;
    if (i >= out_n) return;
    float v = 0.0f;
    if (i < nq) v = qstar[i];
    else if (i - nq < nfeat) v = outb[i - nq];
    dst[i] = v;
}

extern "C" void kernel_launch(void* const* d_in, const int* in_sizes, int n_in,
                              void* d_out, int out_size, void* d_ws, size_t ws_size,
                              hipStream_t stream) {
    constexpr int N = GN, E = GE, B = GB;

    char* ws = (char*)d_ws;
    size_t off = 0;
    auto alloc = [&](size_t bytes) { size_t o = off; off = (off + bytes + 255) & ~(size_t)255; return o; };

    int*   fl     = (int*)  (ws + alloc(19 * 4));
    int*   flagE  = (int*)  (ws + alloc(256));
    int*   flagG  = (int*)  (ws + alloc(256));
    float* counts = (float*)(ws + alloc((size_t)N * 4));
    int*   rowptr = (int*)  (ws + alloc((size_t)(B + 1) * 4));
    float* outbuf = (float*)(ws + alloc((size_t)N * 64 * 4));
    float* agg    = (float*)(ws + alloc((size_t)N * 64 * 4));
    float* qstar  = (float*)(ws + alloc((size_t)B * 128 * 4));
    __hip_bfloat16* h1  = (__hip_bfloat16*)(ws + alloc((size_t)E * 128 * 2));
    __hip_bfloat16* w2P = (__hip_bfloat16*)(ws + alloc((size_t)4096 * 128 * 2));
    __hip_bfloat16* gwp = (__hip_bfloat16*)(ws + alloc((size_t)2 * 12 * 2 * 2 * 512 * 2));

    const int fidx[15]  = {4, 5, 6, 7, 8, 9, 10, 11, 12, 13, 14, 15, 16, 17, 18};
    const int fsize[15] = {75 * 64, 64, 16 * 128, 128, 128 * 4096, 4096, 64,
                           192 * 64, 192 * 64, 192, 192, 256 * 128, 256 * 64, 256, 256};
    float* F[19] = {};
    for (int t = 0; t < 15; ++t) F[fidx[t]] = (float*)(ws + alloc((size_t)fsize[t] * 4));

    DetectArgs da;
    da.src[0] = d_in[0]; da.nhalf[0] = N * 75; da.fi[0] = 0;
    da.src[1] = d_in[1]; da.nhalf[1] = E * 16; da.fi[1] = 1;
    for (int t = 0; t < 15; ++t) { da.src[2 + t] = d_in[fidx[t]]; da.nhalf[2 + t] = fsize[t]; da.fi[2 + t] = fidx[t]; }
    k_detect<<<19, 256, 0, stream>>>(da, (const unsigned int*)d_in[2],
                                     (const unsigned int*)d_in[3], fl, flagE, flagG);

    CvtArgs ca;
    int pre = 0;
    for (int t = 0; t < 15; ++t) {
        ca.src[t] = d_in[fidx[t]]; ca.dst[t] = F[fidx[t]]; ca.n[t] = fsize[t]; ca.fi[t] = fidx[t];
        ca.pre[t] = pre; pre += (fsize[t] + 255) / 256;
    }
    ca.pre[15] = pre;
    k_cvt_all<<<pre, 256, 0, stream>>>(ca, fl);
    k_t2<<<256, 256, 0, stream>>>(d_in[8], w2P, fl + 8);
    k_gpack2<<<12, 256, 0, stream>>>(F[11], F[12], gwp);

    hipMemsetAsync(counts, 0, (size_t)N * 4, stream);
    hipMemsetAsync(qstar, 0, (size_t)B * 128 * 4, stream);

    k_counts<<<E / 256, 256, 0, stream>>>(d_in[2], flagE, counts, E);
    k_rowptr<<<(B + 1 + 255) / 256, 256, 0, stream>>>(d_in[3], flagG, rowptr, N, B);
    k_lin0<<<N / 4, 256, 0, stream>>>(d_in[0], F[4], F[5], outbuf, fl + 0);
    k1_h1<<<E / 2, 256, 0, stream>>>(d_in[1], F[6], F[7], h1, fl + 1);

    for (int it = 0; it < 3; ++it) {
        hipMemsetAsync(agg, 0, (size_t)N * 64 * 4, stream);
        k23_fused<<<E / 128, 512, 0, stream>>>(h1, w2P, F[9], outbuf, d_in[2], flagE, agg);
        k4_gru<<<N / 64, 256, 0, stream>>>(agg, counts, F[10], gwp, F[13], F[14], outbuf);
    }
    k5_fused<<<B, 256, 0, stream>>>(qstar, F[15], F[16], F[17], F[18], outbuf, rowptr);
    k_out<<<(out_size + 255) / 256, 256, 0, stream>>>(qstar, outbuf, (float*)d_out,
                                                      B * 128, N * 64, out_size);
}

// Round 8
// 1053.486 us; speedup vs baseline: 1.7308x; 1.0065x over previous
//
#include <hip/hip_runtime.h>
#include <hip/hip_bf16.h>

#define GN 65536
#define GE 131072
#define GB 2048

typedef __attribute__((ext_vector_type(8))) short short8;
typedef __attribute__((ext_vector_type(4))) float floatx4;

static __device__ __forceinline__ float sigm(float x) { return 1.0f / (1.0f + __expf(-x)); }
static __device__ __forceinline__ float bf2f(unsigned short u) {
    union { unsigned int i; float f; } v; v.i = ((unsigned int)u) << 16; return v.f;
}
static __device__ __forceinline__ int geti(const void* p, long long i, int f64) {
    return f64 ? (int)((const long long*)p)[i] : ((const int*)p)[i];
}

// ---- merged detectors: blocks 0-16 float-dtype, 17 edge-i64, 18 graph-i64 ----
struct DetectArgs { const void* src[17]; int nhalf[17]; int fi[17]; };
__global__ void k_detect(DetectArgs a, const unsigned int* __restrict__ pe,
                         const unsigned int* __restrict__ pg,
                         int* __restrict__ flags, int* __restrict__ flagE,
                         int* __restrict__ flagG) {
    __shared__ unsigned int sA[256], sB[256];
    if (blockIdx.x >= 17) {
        const unsigned int* p = (blockIdx.x == 17) ? pe : pg;
        const long long nwords = (blockIdx.x == 17) ? (long long)2 * GE : (long long)GN;
        const long long lim = nwords < 16384 ? nwords : 16384;
        unsigned int acc = 0;
        for (long long w = 1 + 2 * (long long)threadIdx.x; w < lim; w += 512) acc |= p[w];
        sA[threadIdx.x] = acc;
        __syncthreads();
        for (int st = 128; st > 0; st >>= 1) {
            if (threadIdx.x < st) sA[threadIdx.x] |= sA[threadIdx.x + st];
            __syncthreads();
        }
        if (threadIdx.x == 0) *((blockIdx.x == 17) ? flagE : flagG) = (sA[0] == 0u) ? 1 : 0;
        return;
    }
    const unsigned short* p = (const unsigned short*)a.src[blockIdx.x];
    const int n0 = a.nhalf[blockIdx.x];
    const int n = n0 < 16384 ? n0 : 16384;
    unsigned int any = 0, orEven = 0;
    for (int i = threadIdx.x; i < n; i += 256) {
        const unsigned short u = p[i];
        const float av = fabsf(bf2f(u));
        if (!(av <= 1e6f)) any = 1u;
        if ((i & 1) == 0) orEven |= u;
    }
    sA[threadIdx.x] = any; sB[threadIdx.x] = orEven;
    __syncthreads();
    for (int s = 128; s > 0; s >>= 1) {
        if (threadIdx.x < s) {
            sA[threadIdx.x] |= sA[threadIdx.x + s];
            sB[threadIdx.x] |= sB[threadIdx.x + s];
        }
        __syncthreads();
    }
    if (threadIdx.x == 0) flags[a.fi[blockIdx.x]] = (sA[0] || sB[0] == 0u) ? 1 : 0;
}

// ---- batched f32 canonicalization of the 15 small float tensors ----
struct CvtArgs { const void* src[15]; float* dst[15]; int n[15]; int fi[15]; int pre[16]; };
__global__ void k_cvt_all(CvtArgs a, const int* __restrict__ flags) {
    const int b = blockIdx.x;
    int t = 0;
    while (t < 14 && b >= a.pre[t + 1]) ++t;
    const int i = (b - a.pre[t]) * 256 + threadIdx.x;
    if (i >= a.n[t]) return;
    const int f = flags[a.fi[t]];
    a.dst[t][i] = f ? ((const float*)a.src[t])[i] : bf2f(((const unsigned short*)a.src[t])[i]);
}

// repack w2 [128][4096] -> w2P bf16, COALESCED-FRAGMENT layout:
// group g = ((t*4 + kk)*8 + rb); each wave fragment load is one contiguous 1KB segment.
__global__ __launch_bounds__(256) void k_t2(const void* __restrict__ src,
                                            __hip_bfloat16* __restrict__ w2P,
                                            const int* __restrict__ flag) {
    const int tid8 = blockIdx.x * 256 + threadIdx.x;   // 65536 producers of 8 elems
    const int quad = tid8 & 3, lr = (tid8 >> 2) & 15, rb = (tid8 >> 6) & 7,
              kk = (tid8 >> 9) & 3, t = tid8 >> 11;
    const int n = t * 128 + rb * 16 + lr;              // output col 0..4095
    const int k0 = kk * 32 + quad * 8;                 // k 0..127
    const int isf32 = *flag;
    short8 v;
    #pragma unroll
    for (int j = 0; j < 8; ++j) {
        const size_t si = (size_t)(k0 + j) * 4096 + n;
        const float f = isf32 ? ((const float*)src)[si] : bf2f(((const unsigned short*)src)[si]);
        const __hip_bfloat16 b = __float2bfloat16(f);
        v[j] = *(const short*)&b;
    }
    *(short8*)(w2P + (size_t)tid8 * 8) = v;
}

// pack GRU weights into MFMA B-fragment layout, hi/lo bf16 split.
__global__ void k_gpack2(const float* __restrict__ w_ih, const float* __restrict__ w_hh,
                         __hip_bfloat16* __restrict__ gwp) {
    const int t = blockIdx.x * 256 + threadIdx.x;
    if (t >= 3072) return;
    const int lane = t & 63;
    const int kk = (t >> 6) & 1;
    const int nb = (t >> 7) % 12;
    const int mat = t / 1536;
    const float* W = mat ? w_hh : w_ih;          // [192][64]
    const int c = nb * 16 + (lane & 15);
    const int k0 = kk * 32 + (lane >> 4) * 8;
    short8 hi, lo;
    #pragma unroll
    for (int j = 0; j < 8; ++j) {
        const float v = W[c * 64 + k0 + j];
        const __hip_bfloat16 bh = __float2bfloat16(v);
        hi[j] = *(const short*)&bh;
        const __hip_bfloat16 bl = __float2bfloat16(v - __bfloat162float(bh));
        lo[j] = *(const short*)&bl;
    }
    const size_t base = (size_t)(((mat * 12 + nb) * 2 + kk) * 2);
    *(short8*)(gwp + (base + 0) * 512 + lane * 8) = hi;
    *(short8*)(gwp + (base + 1) * 512 + lane * 8) = lo;
}

__global__ void k_counts(const void* __restrict__ eidx, const int* __restrict__ fi64,
                         float* __restrict__ counts, int E_) {
    int e = blockIdx.x * 256 + threadIdx.x;
    if (e < E_) atomicAdd(&counts[geti(eidx, (long long)E_ + e, *fi64)], 1.0f);
}

__global__ void k_rowptr(const void* __restrict__ gi, const int* __restrict__ fi64,
                         int* __restrict__ rowptr, int N_, int B_) {
    int g = blockIdx.x * 256 + threadIdx.x;
    if (g > B_) return;
    const int f64 = *fi64;
    int lo = 0, hi = N_;
    while (lo < hi) { int mid = (lo + hi) >> 1; if (geti(gi, mid, f64) < g) lo = mid + 1; else hi = mid; }
    rowptr[g] = lo;
}

// lin0: out = relu(nf @ lin0_w + b)
__global__ __launch_bounds__(256) void k_lin0(const void* __restrict__ nf_raw,
                                              const float* __restrict__ w,
                                              const float* __restrict__ b,
                                              float* __restrict__ out,
                                              const int* __restrict__ flag) {
    const int ln = threadIdx.x >> 6;
    const int d = threadIdx.x & 63;
    const int n = blockIdx.x * 4 + ln;
    const int isf32 = *flag;
    __shared__ float s_nf[4][76];
    const size_t base = (size_t)n * 75;
    s_nf[ln][d] = isf32 ? ((const float*)nf_raw)[base + d] : bf2f(((const unsigned short*)nf_raw)[base + d]);
    if (d < 11) s_nf[ln][64 + d] = isf32 ? ((const float*)nf_raw)[base + 64 + d]
                                         : bf2f(((const unsigned short*)nf_raw)[base + 64 + d]);
    __syncthreads();
    float acc = b[d];
    #pragma unroll
    for (int i = 0; i < 75; ++i) acc += s_nf[ln][i] * w[i * 64 + d];
    out[(size_t)n * 64 + d] = fmaxf(acc, 0.0f);
}

// h1 = relu(ef @ w1 + b1) -> bf16, LINEAR layout [e][128]
__global__ __launch_bounds__(256) void k1_h1(const void* __restrict__ ef_raw,
                                             const float* __restrict__ w1,
                                             const float* __restrict__ b1,
                                             __hip_bfloat16* __restrict__ h1,
                                             const int* __restrict__ flag) {
    const int le = threadIdx.x >> 7;
    const int j = threadIdx.x & 127;
    const int e = blockIdx.x * 2 + le;
    const int isf32 = *flag;
    __shared__ float efs[2][16];
    if (j < 16) {
        const size_t idx = (size_t)e * 16 + j;
        efs[le][j] = isf32 ? ((const float*)ef_raw)[idx] : bf2f(((const unsigned short*)ef_raw)[idx]);
    }
    __syncthreads();
    float acc = b1[j];
    #pragma unroll
    for (int i = 0; i < 16; ++i) acc += efs[le][i] * w1[i * 128 + j];
    h1[(size_t)e * 128 + j] = __float2bfloat16(fmaxf(acc, 0.0f));
}

// FUSED NNConv v9: tile-invariant A moved to LDS (XOR-swizzled, staged once)
// so only B occupies named dbuf registers -> allocator slack (r5's VGPR=116
// vs needed 148 serialized the 8 B-loads at full L2 latency: 3975cy/tile).
// Per kk-step: 4 ds_read_b128 (A) + 8 MFMA; B prefetched a full tile ahead,
// pinned with sched_barrier(0). Zero K-loop barriers.
__global__ __launch_bounds__(512) void k23_fused(const __hip_bfloat16* __restrict__ h1,
                                                 const __hip_bfloat16* __restrict__ w2P,
                                                 const float* __restrict__ b2,
                                                 const float* __restrict__ out,
                                                 const void* __restrict__ eidx,
                                                 const int* __restrict__ fi64,
                                                 float* __restrict__ agg) {
    __shared__ __align__(16) __hip_bfloat16 As[128 * 128];   // 32 KB, swizzled
    __shared__ float yT[64][65];                             // 16.6 KB [d][e-half? no: d][row]
    const int tid = threadIdx.x;
    const int e0 = blockIdx.x * 128;
    const int f64 = *fi64;

    const int wave = tid >> 6, lane = tid & 63;
    const int wm = (wave >> 2) * 64;       // 2 M-slices of 64 rows
    const int wn = (wave & 3) * 32;        // 4 N-slices of 32 cols
    const int lr = lane & 15, quad = lane >> 4;

    // stage As swizzled: byte = (r*256 + c*2) ^ ((r&7)<<4)
    {
        const int r = tid >> 2;
        const int cb = (tid & 3) * 32;
        #pragma unroll
        for (int j = 0; j < 4; ++j) {
            const int c = cb + j * 8;
            short8 v = *(const short8*)(h1 + (size_t)(e0 + r) * 128 + c);
            const int byte = (r * 256 + c * 2) ^ ((r & 7) << 4);
            *(short8*)((char*)As + byte) = v;
        }
    }
    // stage yT[d][e] = out[src[e]][d]  (note: yT[64 d][64+1 rows-of-128?];
    // block has 128 edges -> yT[d][e] with e 0..127 needs [64][129]; but
    // epilogue reads rows (edges). Keep [64][129] layout semantics:
    // we store y for all 128 edges: use two halves via yT2 below.
    __shared__ float yT2[64][129];
    {
        const int e = tid >> 2, d0 = (tid & 3) * 16;
        const int s = geti(eidx, e0 + e, f64);
        const float* srow = out + (size_t)s * 64 + d0;
        #pragma unroll
        for (int j = 0; j < 4; ++j) {
            float4 v = *(const float4*)(srow + j * 4);
            yT2[d0 + j * 4 + 0][e] = v.x;
            yT2[d0 + j * 4 + 1][e] = v.y;
            yT2[d0 + j * 4 + 2][e] = v.z;
            yT2[d0 + j * 4 + 3][e] = v.w;
        }
    }
    __syncthreads();                 // As + yT ready; the ONLY barrier

    const int lin = (lr * 4 + quad) * 8;   // lane offset inside a 512-elem group
    const int sxa = (lr & 7) << 4;         // A-read swizzle (row&7 == lr&7)
    float msum[4][2][4] = {};

#define K23_LOADB(dst, tt)                                                      \
    _Pragma("unroll")                                                           \
    for (int kk = 0; kk < 4; ++kk) {                                            \
        _Pragma("unroll")                                                       \
        for (int nt = 0; nt < 2; ++nt) {                                        \
            const int g = ((tt) * 4 + kk) * 8 + (wn >> 4) + nt;                 \
            dst[kk][nt] = *(const short8*)(w2P + (size_t)g * 512 + lin);        \
        }                                                                       \
    }                                                                           \
    __builtin_amdgcn_sched_barrier(0);

#define K23_BODY(tt, buf) {                                                     \
    const int n0 = (tt) * 128;                                                  \
    const int dcur = (n0 + wn) >> 6;                                            \
    const float b2v0 = b2[n0 + wn + lr];                                        \
    const float b2v1 = b2[n0 + wn + 16 + lr];                                   \
    floatx4 acc[4][2] = {};                                                     \
    _Pragma("unroll")                                                           \
    for (int kk = 0; kk < 4; ++kk) {                                            \
        short8 a0, a1, a2, a3;                                                  \
        {                                                                       \
            const int cb = kk * 64 + quad * 16;                                 \
            a0 = *(const short8*)((const char*)As + (((wm + 0 * 16 + lr) * 256 + cb) ^ sxa)); \
            a1 = *(const short8*)((const char*)As + (((wm + 1 * 16 + lr) * 256 + cb) ^ sxa)); \
            a2 = *(const short8*)((const char*)As + (((wm + 2 * 16 + lr) * 256 + cb) ^ sxa)); \
            a3 = *(const short8*)((const char*)As + (((wm + 3 * 16 + lr) * 256 + cb) ^ sxa)); \
        }                                                                       \
        __builtin_amdgcn_s_setprio(1);                                          \
        acc[0][0] = __builtin_amdgcn_mfma_f32_16x16x32_bf16(a0, buf[kk][0], acc[0][0], 0, 0, 0); \
        acc[0][1] = __builtin_amdgcn_mfma_f32_16x16x32_bf16(a0, buf[kk][1], acc[0][1], 0, 0, 0); \
        acc[1][0] = __builtin_amdgcn_mfma_f32_16x16x32_bf16(a1, buf[kk][0], acc[1][0], 0, 0, 0); \
        acc[1][1] = __builtin_amdgcn_mfma_f32_16x16x32_bf16(a1, buf[kk][1], acc[1][1], 0, 0, 0); \
        acc[2][0] = __builtin_amdgcn_mfma_f32_16x16x32_bf16(a2, buf[kk][0], acc[2][0], 0, 0, 0); \
        acc[2][1] = __builtin_amdgcn_mfma_f32_16x16x32_bf16(a2, buf[kk][1], acc[2][1], 0, 0, 0); \
        acc[3][0] = __builtin_amdgcn_mfma_f32_16x16x32_bf16(a3, buf[kk][0], acc[3][0], 0, 0, 0); \
        acc[3][1] = __builtin_amdgcn_mfma_f32_16x16x32_bf16(a3, buf[kk][1], acc[3][1], 0, 0, 0); \
        __builtin_amdgcn_s_setprio(0);                                          \
    }                                                                           \
    _Pragma("unroll")                                                           \
    for (int mt = 0; mt < 4; ++mt) {                                            \
        _Pragma("unroll")                                                       \
        for (int r = 0; r < 4; ++r) {                                           \
            const float yv = yT2[dcur][wm + mt * 16 + quad * 4 + r];            \
            msum[mt][0][r] = fmaf(yv, acc[mt][0][r] + b2v0, msum[mt][0][r]);    \
            msum[mt][1][r] = fmaf(yv, acc[mt][1][r] + b2v1, msum[mt][1][r]);    \
        }                                                                       \
    }                                                                           \
}

    short8 bA[4][2], bB[4][2];
    K23_LOADB(bA, 0)
    #pragma unroll 1
    for (int t = 0; t < 32; t += 2) {
        K23_LOADB(bB, t + 1)          // in flight across BODY(t)
        K23_BODY(t, bA)
        if (t + 2 < 32) { K23_LOADB(bA, t + 2) }  // in flight across BODY(t+1)
        K23_BODY(t + 1, bB)
    }
#undef K23_LOADB
#undef K23_BODY

    const int fbase = (wn & 32);
    #pragma unroll
    for (int mt = 0; mt < 4; ++mt)
        #pragma unroll
        for (int r = 0; r < 4; ++r) {
            const int row = wm + mt * 16 + quad * 4 + r;
            const int dn = geti(eidx, (long long)GE + e0 + row, f64);
            #pragma unroll
            for (int nt = 0; nt < 2; ++nt)
                atomicAdd(&agg[(size_t)dn * 64 + fbase + nt * 16 + lr], msum[mt][nt][r]);
        }
}

// GRU v4: MFMA gate GEMMs (r7-verified).
__global__ __launch_bounds__(256) void k4_gru(const float* __restrict__ agg,
                                              const float* __restrict__ counts,
                                              const float* __restrict__ cbias,
                                              const __hip_bfloat16* __restrict__ gwp,
                                              const float* __restrict__ b_ih,
                                              const float* __restrict__ b_hh,
                                              float* __restrict__ out) {
    const int wv = threadIdx.x >> 6, lane = threadIdx.x & 63;
    const int lr = lane & 15, quad = lane >> 4;
    const int wnb0 = blockIdx.x * 64 + wv * 16;
    const int node = wnb0 + lr;

    const float rcnt = 1.0f / fmaxf(counts[node], 1.0f);
    const float* ap = agg + (size_t)node * 64;
    const float* hp = out + (size_t)node * 64;
    short8 am[2], ah[2];
    #pragma unroll
    for (int kk = 0; kk < 2; ++kk) {
        const int k0 = kk * 32 + quad * 8;
        #pragma unroll
        for (int j = 0; j < 8; ++j) {
            const float mv = fmaxf(ap[k0 + j] * rcnt + cbias[k0 + j], 0.0f);
            const __hip_bfloat16 mb = __float2bfloat16(mv);
            am[kk][j] = *(const short*)&mb;
            const __hip_bfloat16 hb = __float2bfloat16(hp[k0 + j]);
            ah[kk][j] = *(const short*)&hb;
        }
    }

    floatx4 ai[12] = {}, ahh[12] = {};
    #pragma unroll
    for (int nb = 0; nb < 12; ++nb) {
        #pragma unroll
        for (int kk = 0; kk < 2; ++kk) {
            #pragma unroll
            for (int part = 0; part < 2; ++part) {
                const short8 bi = *(const short8*)(gwp + (size_t)(((0 * 12 + nb) * 2 + kk) * 2 + part) * 512 + lane * 8);
                ai[nb] = __builtin_amdgcn_mfma_f32_16x16x32_bf16(am[kk], bi, ai[nb], 0, 0, 0);
                const short8 bh = *(const short8*)(gwp + (size_t)(((1 * 12 + nb) * 2 + kk) * 2 + part) * 512 + lane * 8);
                ahh[nb] = __builtin_amdgcn_mfma_f32_16x16x32_bf16(ah[kk], bh, ahh[nb], 0, 0, 0);
            }
        }
    }

    #pragma unroll
    for (int f = 0; f < 4; ++f) {
        const int d = f * 16 + lr;
        const float bir = b_ih[d],       bhr = b_hh[d];
        const float biz = b_ih[64 + d],  bhz = b_hh[64 + d];
        const float bin = b_ih[128 + d], bhn = b_hh[128 + d];
        #pragma unroll
        for (int r = 0; r < 4; ++r) {
            const int row = wnb0 + quad * 4 + r;
            const float rr = sigm(ai[f][r] + bir + ahh[f][r] + bhr);
            const float zz = sigm(ai[f + 4][r] + biz + ahh[f + 4][r] + bhz);
            const float nn = tanhf(ai[f + 8][r] + bin + rr * (ahh[f + 8][r] + bhn));
            const float hd = out[(size_t)row * 64 + d];
            out[(size_t)row * 64 + d] = (1.0f - zz) * nn + zz * hd;
        }
    }
}

// FUSED Set2Set: all 3 processing steps in ONE launch.
__global__ __launch_bounds__(256) void k5_fused(float* __restrict__ qstar,
                                                const float* __restrict__ w_ih,
                                                const float* __restrict__ w_hh,
                                                const float* __restrict__ b_ih,
                                                const float* __restrict__ b_hh,
                                                const float* __restrict__ out,
                                                const int* __restrict__ rowptr) {
    const int g = blockIdx.x;
    const int j = threadIdx.x;
    __shared__ float qs[128], hv[64], gates[256];
    __shared__ float smw[4], sSw[4], srw[4][64];
    if (j < 128) qs[j] = 0.0f;
    if (j < 64) hv[j] = 0.0f;
    float creg = 0.0f;               // cs state (threads j<64)
    const int wv = j >> 6, lane = j & 63;
    const int start = rowptr[g], end = rowptr[g + 1];
    const float bsum = b_ih[j] + b_hh[j];

    for (int step = 0; step < 3; ++step) {
        __syncthreads();             // qs/hv (and smw/srw reuse) ready
        float acc = bsum;
        for (int k4 = 0; k4 < 128; k4 += 4) {
            float4 v = *(const float4*)(w_ih + (size_t)j * 128 + k4);
            const float* pv = (const float*)&v;
            #pragma unroll
            for (int t = 0; t < 4; ++t) acc += qs[k4 + t] * pv[t];
        }
        for (int k4 = 0; k4 < 64; k4 += 4) {
            float4 v = *(const float4*)(w_hh + (size_t)j * 64 + k4);
            const float* pv = (const float*)&v;
            #pragma unroll
            for (int t = 0; t < 4; ++t) acc += hv[k4 + t] * pv[t];
        }
        gates[j] = acc;
        __syncthreads();
        if (j < 64) {
            const float ig = sigm(gates[j]);
            const float fg = sigm(gates[64 + j]);
            const float gg = tanhf(gates[128 + j]);
            const float og = sigm(gates[192 + j]);
            creg = fg * creg + ig * gg;
            const float h = og * tanhf(creg);
            hv[j] = h;
            qs[j] = h;
        }
        __syncthreads();
        // attention: wave wv handles nodes start+wv, start+wv+4, ...
        const float q = hv[lane];
        float m = -3.4e38f, S = 0.0f, racc = 0.0f;
        for (int n = start + wv; n < end; n += 4) {
            const float ov = out[(size_t)n * 64 + lane];
            float p = ov * q;
            #pragma unroll
            for (int off = 1; off < 64; off <<= 1) p += __shfl_xor(p, off);
            if (p > m) {
                const float sc = __expf(m - p);
                S = S * sc + 1.0f;
                racc = racc * sc + ov;
                m = p;
            } else {
                const float w = __expf(p - m);
                S += w;
                racc += w * ov;
            }
        }
        if (lane == 0) { smw[wv] = m; sSw[wv] = S; }
        srw[wv][lane] = racc;
        __syncthreads();
        if (wv == 0) {
            const float mstar = fmaxf(fmaxf(smw[0], smw[1]), fmaxf(smw[2], smw[3]));
            float Ssum = 0.0f, rsum = 0.0f;
            #pragma unroll
            for (int i = 0; i < 4; ++i) {
                const float sc = __expf(smw[i] - mstar);   // empty wave: exp(-huge)=0
                Ssum += sSw[i] * sc;
                rsum += srw[i][lane] * sc;
            }
            qs[64 + lane] = rsum / (Ssum + 1e-16f);
        }
    }
    __syncthreads();
    if (j < 128) qstar[(size_t)g * 128 + j] = qs[j];
}

__global__ void k_out(const float* __restrict__ qstar, const float* __restrict__ outb,
                      float* __restrict__ dst, int nq, int nfeat, int out_n) {
    int i = blockIdx.x * 256 + threadIdx.x;
    if (i >= out_n) return;
    float v = 0.0f;
    if (i < nq) v = qstar[i];
    else if (i - nq < nfeat) v = outb[i - nq];
    dst[i] = v;
}

extern "C" void kernel_launch(void* const* d_in, const int* in_sizes, int n_in,
                              void* d_out, int out_size, void* d_ws, size_t ws_size,
                              hipStream_t stream) {
    constexpr int N = GN, E = GE, B = GB;

    char* ws = (char*)d_ws;
    size_t off = 0;
    auto alloc = [&](size_t bytes) { size_t o = off; off = (off + bytes + 255) & ~(size_t)255; return o; };

    int*   fl     = (int*)  (ws + alloc(19 * 4));
    int*   flagE  = (int*)  (ws + alloc(256));
    int*   flagG  = (int*)  (ws + alloc(256));
    float* counts = (float*)(ws + alloc((size_t)N * 4));
    int*   rowptr = (int*)  (ws + alloc((size_t)(B + 1) * 4));
    float* outbuf = (float*)(ws + alloc((size_t)N * 64 * 4));
    float* agg    = (float*)(ws + alloc((size_t)N * 64 * 4));
    float* qstar  = (float*)(ws + alloc((size_t)B * 128 * 4));
    __hip_bfloat16* h1  = (__hip_bfloat16*)(ws + alloc((size_t)E * 128 * 2));
    __hip_bfloat16* w2P = (__hip_bfloat16*)(ws + alloc((size_t)4096 * 128 * 2));
    __hip_bfloat16* gwp = (__hip_bfloat16*)(ws + alloc((size_t)2 * 12 * 2 * 2 * 512 * 2));

    const int fidx[15]  = {4, 5, 6, 7, 8, 9, 10, 11, 12, 13, 14, 15, 16, 17, 18};
    const int fsize[15] = {75 * 64, 64, 16 * 128, 128, 128 * 4096, 4096, 64,
                           192 * 64, 192 * 64, 192, 192, 256 * 128, 256 * 64, 256, 256};
    float* F[19] = {};
    for (int t = 0; t < 15; ++t) F[fidx[t]] = (float*)(ws + alloc((size_t)fsize[t] * 4));

    DetectArgs da;
    da.src[0] = d_in[0]; da.nhalf[0] = N * 75; da.fi[0] = 0;
    da.src[1] = d_in[1]; da.nhalf[1] = E * 16; da.fi[1] = 1;
    for (int t = 0; t < 15; ++t) { da.src[2 + t] = d_in[fidx[t]]; da.nhalf[2 + t] = fsize[t]; da.fi[2 + t] = fidx[t]; }
    k_detect<<<19, 256, 0, stream>>>(da, (const unsigned int*)d_in[2],
                                     (const unsigned int*)d_in[3], fl, flagE, flagG);

    CvtArgs ca;
    int pre = 0;
    for (int t = 0; t < 15; ++t) {
        ca.src[t] = d_in[fidx[t]]; ca.dst[t] = F[fidx[t]]; ca.n[t] = fsize[t]; ca.fi[t] = fidx[t];
        ca.pre[t] = pre; pre += (fsize[t] + 255) / 256;
    }
    ca.pre[15] = pre;
    k_cvt_all<<<pre, 256, 0, stream>>>(ca, fl);
    k_t2<<<256, 256, 0, stream>>>(d_in[8], w2P, fl + 8);
    k_gpack2<<<12, 256, 0, stream>>>(F[11], F[12], gwp);

    hipMemsetAsync(counts, 0, (size_t)N * 4, stream);
    hipMemsetAsync(qstar, 0, (size_t)B * 128 * 4, stream);

    k_counts<<<E / 256, 256, 0, stream>>>(d_in[2], flagE, counts, E);
    k_rowptr<<<(B + 1 + 255) / 256, 256, 0, stream>>>(d_in[3], flagG, rowptr, N, B);
    k_lin0<<<N / 4, 256, 0, stream>>>(d_in[0], F[4], F[5], outbuf, fl + 0);
    k1_h1<<<E / 2, 256, 0, stream>>>(d_in[1], F[6], F[7], h1, fl + 1);

    for (int it = 0; it < 3; ++it) {
        hipMemsetAsync(agg, 0, (size_t)N * 64 * 4, stream);
        k23_fused<<<E / 128, 512, 0, stream>>>(h1, w2P, F[9], outbuf, d_in[2], flagE, agg);
        k4_gru<<<N / 64, 256, 0, stream>>>(agg, counts, F[10], gwp, F[13], F[14], outbuf);
    }
    k5_fused<<<B, 256, 0, stream>>>(qstar, F[15], F[16], F[17], F[18], outbuf, rowptr);
    k_out<<<(out_size + 255) / 256, 256, 0, stream>>>(qstar, outbuf, (float*)d_out,
                                                      B * 128, N * 64, out_size);
}

// Round 9
// 972.639 us; speedup vs baseline: 1.8747x; 1.0831x over previous
//
#include <hip/hip_runtime.h>
#include <hip/hip_bf16.h>

#define GN 65536
#define GE 131072
#define GB 2048

typedef __attribute__((ext_vector_type(8))) short short8;
typedef __attribute__((ext_vector_type(4))) float floatx4;

static __device__ __forceinline__ float sigm(float x) { return 1.0f / (1.0f + __expf(-x)); }
static __device__ __forceinline__ float bf2f(unsigned short u) {
    union { unsigned int i; float f; } v; v.i = ((unsigned int)u) << 16; return v.f;
}
static __device__ __forceinline__ int geti(const void* p, long long i, int f64) {
    return f64 ? (int)((const long long*)p)[i] : ((const int*)p)[i];
}

// ---- merged detectors: blocks 0-16 float-dtype, 17 edge-i64, 18 graph-i64 ----
struct DetectArgs { const void* src[17]; int nhalf[17]; int fi[17]; };
__global__ void k_detect(DetectArgs a, const unsigned int* __restrict__ pe,
                         const unsigned int* __restrict__ pg,
                         int* __restrict__ flags, int* __restrict__ flagE,
                         int* __restrict__ flagG) {
    __shared__ unsigned int sA[256], sB[256];
    if (blockIdx.x >= 17) {
        const unsigned int* p = (blockIdx.x == 17) ? pe : pg;
        const long long nwords = (blockIdx.x == 17) ? (long long)2 * GE : (long long)GN;
        const long long lim = nwords < 16384 ? nwords : 16384;
        unsigned int acc = 0;
        for (long long w = 1 + 2 * (long long)threadIdx.x; w < lim; w += 512) acc |= p[w];
        sA[threadIdx.x] = acc;
        __syncthreads();
        for (int st = 128; st > 0; st >>= 1) {
            if (threadIdx.x < st) sA[threadIdx.x] |= sA[threadIdx.x + st];
            __syncthreads();
        }
        if (threadIdx.x == 0) *((blockIdx.x == 17) ? flagE : flagG) = (sA[0] == 0u) ? 1 : 0;
        return;
    }
    const unsigned short* p = (const unsigned short*)a.src[blockIdx.x];
    const int n0 = a.nhalf[blockIdx.x];
    const int n = n0 < 16384 ? n0 : 16384;
    unsigned int any = 0, orEven = 0;
    for (int i = threadIdx.x; i < n; i += 256) {
        const unsigned short u = p[i];
        const float av = fabsf(bf2f(u));
        if (!(av <= 1e6f)) any = 1u;
        if ((i & 1) == 0) orEven |= u;
    }
    sA[threadIdx.x] = any; sB[threadIdx.x] = orEven;
    __syncthreads();
    for (int s = 128; s > 0; s >>= 1) {
        if (threadIdx.x < s) {
            sA[threadIdx.x] |= sA[threadIdx.x + s];
            sB[threadIdx.x] |= sB[threadIdx.x + s];
        }
        __syncthreads();
    }
    if (threadIdx.x == 0) flags[a.fi[blockIdx.x]] = (sA[0] || sB[0] == 0u) ? 1 : 0;
}

// ---- batched f32 canonicalization of the 15 small float tensors ----
struct CvtArgs { const void* src[15]; float* dst[15]; int n[15]; int fi[15]; int pre[16]; };
__global__ void k_cvt_all(CvtArgs a, const int* __restrict__ flags) {
    const int b = blockIdx.x;
    int t = 0;
    while (t < 14 && b >= a.pre[t + 1]) ++t;
    const int i = (b - a.pre[t]) * 256 + threadIdx.x;
    if (i >= a.n[t]) return;
    const int f = flags[a.fi[t]];
    a.dst[t][i] = f ? ((const float*)a.src[t])[i] : bf2f(((const unsigned short*)a.src[t])[i]);
}

// repack w2 [128][4096] -> w2P bf16, COALESCED-FRAGMENT layout:
// group g = ((t*4 + kk)*8 + rb); each wave fragment load is one contiguous 1KB segment.
__global__ __launch_bounds__(256) void k_t2(const void* __restrict__ src,
                                            __hip_bfloat16* __restrict__ w2P,
                                            const int* __restrict__ flag) {
    const int tid8 = blockIdx.x * 256 + threadIdx.x;   // 65536 producers of 8 elems
    const int quad = tid8 & 3, lr = (tid8 >> 2) & 15, rb = (tid8 >> 6) & 7,
              kk = (tid8 >> 9) & 3, t = tid8 >> 11;
    const int n = t * 128 + rb * 16 + lr;              // output col 0..4095
    const int k0 = kk * 32 + quad * 8;                 // k 0..127
    const int isf32 = *flag;
    short8 v;
    #pragma unroll
    for (int j = 0; j < 8; ++j) {
        const size_t si = (size_t)(k0 + j) * 4096 + n;
        const float f = isf32 ? ((const float*)src)[si] : bf2f(((const unsigned short*)src)[si]);
        const __hip_bfloat16 b = __float2bfloat16(f);
        v[j] = *(const short*)&b;
    }
    *(short8*)(w2P + (size_t)tid8 * 8) = v;
}

// pack GRU weights into MFMA B-fragment layout, hi/lo bf16 split.
__global__ void k_gpack2(const float* __restrict__ w_ih, const float* __restrict__ w_hh,
                         __hip_bfloat16* __restrict__ gwp) {
    const int t = blockIdx.x * 256 + threadIdx.x;
    if (t >= 3072) return;
    const int lane = t & 63;
    const int kk = (t >> 6) & 1;
    const int nb = (t >> 7) % 12;
    const int mat = t / 1536;
    const float* W = mat ? w_hh : w_ih;          // [192][64]
    const int c = nb * 16 + (lane & 15);
    const int k0 = kk * 32 + (lane >> 4) * 8;
    short8 hi, lo;
    #pragma unroll
    for (int j = 0; j < 8; ++j) {
        const float v = W[c * 64 + k0 + j];
        const __hip_bfloat16 bh = __float2bfloat16(v);
        hi[j] = *(const short*)&bh;
        const __hip_bfloat16 bl = __float2bfloat16(v - __bfloat162float(bh));
        lo[j] = *(const short*)&bl;
    }
    const size_t base = (size_t)(((mat * 12 + nb) * 2 + kk) * 2);
    *(short8*)(gwp + (base + 0) * 512 + lane * 8) = hi;
    *(short8*)(gwp + (base + 1) * 512 + lane * 8) = lo;
}

__global__ void k_counts(const void* __restrict__ eidx, const int* __restrict__ fi64,
                         float* __restrict__ counts, int E_) {
    int e = blockIdx.x * 256 + threadIdx.x;
    if (e < E_) atomicAdd(&counts[geti(eidx, (long long)E_ + e, *fi64)], 1.0f);
}

__global__ void k_rowptr(const void* __restrict__ gi, const int* __restrict__ fi64,
                         int* __restrict__ rowptr, int N_, int B_) {
    int g = blockIdx.x * 256 + threadIdx.x;
    if (g > B_) return;
    const int f64 = *fi64;
    int lo = 0, hi = N_;
    while (lo < hi) { int mid = (lo + hi) >> 1; if (geti(gi, mid, f64) < g) lo = mid + 1; else hi = mid; }
    rowptr[g] = lo;
}

// lin0: out = relu(nf @ lin0_w + b)
__global__ __launch_bounds__(256) void k_lin0(const void* __restrict__ nf_raw,
                                              const float* __restrict__ w,
                                              const float* __restrict__ b,
                                              float* __restrict__ out,
                                              const int* __restrict__ flag) {
    const int ln = threadIdx.x >> 6;
    const int d = threadIdx.x & 63;
    const int n = blockIdx.x * 4 + ln;
    const int isf32 = *flag;
    __shared__ float s_nf[4][76];
    const size_t base = (size_t)n * 75;
    s_nf[ln][d] = isf32 ? ((const float*)nf_raw)[base + d] : bf2f(((const unsigned short*)nf_raw)[base + d]);
    if (d < 11) s_nf[ln][64 + d] = isf32 ? ((const float*)nf_raw)[base + 64 + d]
                                         : bf2f(((const unsigned short*)nf_raw)[base + 64 + d]);
    __syncthreads();
    float acc = b[d];
    #pragma unroll
    for (int i = 0; i < 75; ++i) acc += s_nf[ln][i] * w[i * 64 + d];
    out[(size_t)n * 64 + d] = fmaxf(acc, 0.0f);
}

// h1 = relu(ef @ w1 + b1) -> bf16, LINEAR layout [e][128]
__global__ __launch_bounds__(256) void k1_h1(const void* __restrict__ ef_raw,
                                             const float* __restrict__ w1,
                                             const float* __restrict__ b1,
                                             __hip_bfloat16* __restrict__ h1,
                                             const int* __restrict__ flag) {
    const int le = threadIdx.x >> 7;
    const int j = threadIdx.x & 127;
    const int e = blockIdx.x * 2 + le;
    const int isf32 = *flag;
    __shared__ float efs[2][16];
    if (j < 16) {
        const size_t idx = (size_t)e * 16 + j;
        efs[le][j] = isf32 ? ((const float*)ef_raw)[idx] : bf2f(((const unsigned short*)ef_raw)[idx]);
    }
    __syncthreads();
    float acc = b1[j];
    #pragma unroll
    for (int i = 0; i < 16; ++i) acc += efs[le][i] * w1[i * 128 + j];
    h1[(size_t)e * 128 + j] = __float2bfloat16(fmaxf(acc, 0.0f));
}

// FUSED NNConv v10: 4-wave blocks (64 edges). Per-wave math identical to r8
// (Mw=64 -> wm=0, Nw=32, B dbuf regs, A from swizzled LDS) but the block
// quantum shrinks so 3 blocks/CU co-reside at ~156 regs/thread (r8: one
// 8-wave block/CU, 2 waves/SIMD, nothing hides latency -> 4x52us = 210us).
// Independent blocks interleave freely (no shared barrier). Epilogue merges
// the intrinsic 2x f-fold (n and n+64 -> same f) in LDS (As aliased) ->
// single set of atomics (halves atomic HBM writes).
__global__ __launch_bounds__(256) void k23_fused(const __hip_bfloat16* __restrict__ h1,
                                                 const __hip_bfloat16* __restrict__ w2P,
                                                 const float* __restrict__ b2,
                                                 const float* __restrict__ out,
                                                 const void* __restrict__ eidx,
                                                 const int* __restrict__ fi64,
                                                 float* __restrict__ agg) {
    __shared__ __align__(16) __hip_bfloat16 As[64 * 128];   // 16 KB, swizzled; aliased as merge buf
    __shared__ float yT[64][65];                            // 16.6 KB [d][e]
    __shared__ int sdx[64];                                 // dst indices
    const int tid = threadIdx.x;
    const int e0 = blockIdx.x * 64;
    const int f64 = *fi64;

    const int wave = tid >> 6, lane = tid & 63;
    const int wn = wave * 32;              // 4 N-slices of 32 cols
    const int lr = lane & 15, quad = lane >> 4;

    if (tid < 64) sdx[tid] = geti(eidx, (long long)GE + e0 + tid, f64);
    // stage As swizzled: byte = (r*256 + c*2) ^ ((r&7)<<4)
    {
        const int r = tid >> 2;
        const int cb = (tid & 3) * 32;
        #pragma unroll
        for (int j = 0; j < 4; ++j) {
            const int c = cb + j * 8;
            short8 v = *(const short8*)(h1 + (size_t)(e0 + r) * 128 + c);
            const int byte = (r * 256 + c * 2) ^ ((r & 7) << 4);
            *(short8*)((char*)As + byte) = v;
        }
    }
    // stage yT[d][e] = out[src[e]][d]
    {
        const int e = tid >> 2, d0 = (tid & 3) * 16;
        const int s = geti(eidx, e0 + e, f64);
        const float* srow = out + (size_t)s * 64 + d0;
        #pragma unroll
        for (int j = 0; j < 4; ++j) {
            float4 v = *(const float4*)(srow + j * 4);
            yT[d0 + j * 4 + 0][e] = v.x;
            yT[d0 + j * 4 + 1][e] = v.y;
            yT[d0 + j * 4 + 2][e] = v.z;
            yT[d0 + j * 4 + 3][e] = v.w;
        }
    }
    __syncthreads();

    const int lin = (lr * 4 + quad) * 8;   // lane offset inside a 512-elem group
    const int sxa = (lr & 7) << 4;         // A-read swizzle (row&7 == lr&7)
    float msum[4][2][4] = {};

#define K23_LOADB(dst, tt)                                                      \
    _Pragma("unroll")                                                           \
    for (int kk = 0; kk < 4; ++kk) {                                            \
        _Pragma("unroll")                                                       \
        for (int nt = 0; nt < 2; ++nt) {                                        \
            const int g = ((tt) * 4 + kk) * 8 + (wn >> 4) + nt;                 \
            dst[kk][nt] = *(const short8*)(w2P + (size_t)g * 512 + lin);        \
        }                                                                       \
    }                                                                           \
    __builtin_amdgcn_sched_barrier(0);

#define K23_BODY(tt, buf) {                                                     \
    const int n0 = (tt) * 128;                                                  \
    const int dcur = (n0 + wn) >> 6;                                            \
    const float b2v0 = b2[n0 + wn + lr];                                        \
    const float b2v1 = b2[n0 + wn + 16 + lr];                                   \
    floatx4 acc[4][2] = {};                                                     \
    _Pragma("unroll")                                                           \
    for (int kk = 0; kk < 4; ++kk) {                                            \
        short8 a0, a1, a2, a3;                                                  \
        {                                                                       \
            const int cb = kk * 64 + quad * 16;                                 \
            a0 = *(const short8*)((const char*)As + (((0 * 16 + lr) * 256 + cb) ^ sxa)); \
            a1 = *(const short8*)((const char*)As + (((1 * 16 + lr) * 256 + cb) ^ sxa)); \
            a2 = *(const short8*)((const char*)As + (((2 * 16 + lr) * 256 + cb) ^ sxa)); \
            a3 = *(const short8*)((const char*)As + (((3 * 16 + lr) * 256 + cb) ^ sxa)); \
        }                                                                       \
        __builtin_amdgcn_s_setprio(1);                                          \
        acc[0][0] = __builtin_amdgcn_mfma_f32_16x16x32_bf16(a0, buf[kk][0], acc[0][0], 0, 0, 0); \
        acc[0][1] = __builtin_amdgcn_mfma_f32_16x16x32_bf16(a0, buf[kk][1], acc[0][1], 0, 0, 0); \
        acc[1][0] = __builtin_amdgcn_mfma_f32_16x16x32_bf16(a1, buf[kk][0], acc[1][0], 0, 0, 0); \
        acc[1][1] = __builtin_amdgcn_mfma_f32_16x16x32_bf16(a1, buf[kk][1], acc[1][1], 0, 0, 0); \
        acc[2][0] = __builtin_amdgcn_mfma_f32_16x16x32_bf16(a2, buf[kk][0], acc[2][0], 0, 0, 0); \
        acc[2][1] = __builtin_amdgcn_mfma_f32_16x16x32_bf16(a2, buf[kk][1], acc[2][1], 0, 0, 0); \
        acc[3][0] = __builtin_amdgcn_mfma_f32_16x16x32_bf16(a3, buf[kk][0], acc[3][0], 0, 0, 0); \
        acc[3][1] = __builtin_amdgcn_mfma_f32_16x16x32_bf16(a3, buf[kk][1], acc[3][1], 0, 0, 0); \
        __builtin_amdgcn_s_setprio(0);                                          \
    }                                                                           \
    _Pragma("unroll")                                                           \
    for (int mt = 0; mt < 4; ++mt) {                                            \
        _Pragma("unroll")                                                       \
        for (int r = 0; r < 4; ++r) {                                           \
            const float yv = yT[dcur][mt * 16 + quad * 4 + r];                  \
            msum[mt][0][r] = fmaf(yv, acc[mt][0][r] + b2v0, msum[mt][0][r]);    \
            msum[mt][1][r] = fmaf(yv, acc[mt][1][r] + b2v1, msum[mt][1][r]);    \
        }                                                                       \
    }                                                                           \
}

    short8 bA[4][2], bB[4][2];
    K23_LOADB(bA, 0)
    #pragma unroll 1
    for (int t = 0; t < 32; t += 2) {
        K23_LOADB(bB, t + 1)          // in flight across BODY(t)
        K23_BODY(t, bA)
        if (t + 2 < 32) { K23_LOADB(bA, t + 2) }  // in flight across BODY(t+1)
        K23_BODY(t + 1, bB)
    }
#undef K23_LOADB
#undef K23_BODY

    // merged epilogue: fold wave-pair (wn, wn+64) partials in LDS, then
    // one coalesced atomicAdd set. As (16KB) aliased as 64x64 f32 merge buf.
    __syncthreads();                       // all waves done with As/yT
    float* mg = (float*)As;
    const int fb = (wn & 32);
    if (wave < 2) {
        #pragma unroll
        for (int mt = 0; mt < 4; ++mt)
            #pragma unroll
            for (int r = 0; r < 4; ++r)
                #pragma unroll
                for (int nt = 0; nt < 2; ++nt)
                    mg[(mt * 16 + quad * 4 + r) * 64 + fb + nt * 16 + lr] = msum[mt][nt][r];
    }
    __syncthreads();
    if (wave >= 2) {
        #pragma unroll
        for (int mt = 0; mt < 4; ++mt)
            #pragma unroll
            for (int r = 0; r < 4; ++r)
                #pragma unroll
                for (int nt = 0; nt < 2; ++nt)
                    mg[(mt * 16 + quad * 4 + r) * 64 + fb + nt * 16 + lr] += msum[mt][nt][r];
    }
    __syncthreads();
    #pragma unroll
    for (int i = 0; i < 16; ++i) {
        const int o = i * 256 + tid;
        const int row = o >> 6, col = o & 63;
        atomicAdd(&agg[(size_t)sdx[row] * 64 + col], mg[o]);
    }
}

// GRU v4: MFMA gate GEMMs (r7-verified).
__global__ __launch_bounds__(256) void k4_gru(const float* __restrict__ agg,
                                              const float* __restrict__ counts,
                                              const float* __restrict__ cbias,
                                              const __hip_bfloat16* __restrict__ gwp,
                                              const float* __restrict__ b_ih,
                                              const float* __restrict__ b_hh,
                                              float* __restrict__ out) {
    const int wv = threadIdx.x >> 6, lane = threadIdx.x & 63;
    const int lr = lane & 15, quad = lane >> 4;
    const int wnb0 = blockIdx.x * 64 + wv * 16;
    const int node = wnb0 + lr;

    const float rcnt = 1.0f / fmaxf(counts[node], 1.0f);
    const float* ap = agg + (size_t)node * 64;
    const float* hp = out + (size_t)node * 64;
    short8 am[2], ah[2];
    #pragma unroll
    for (int kk = 0; kk < 2; ++kk) {
        const int k0 = kk * 32 + quad * 8;
        #pragma unroll
        for (int j = 0; j < 8; ++j) {
            const float mv = fmaxf(ap[k0 + j] * rcnt + cbias[k0 + j], 0.0f);
            const __hip_bfloat16 mb = __float2bfloat16(mv);
            am[kk][j] = *(const short*)&mb;
            const __hip_bfloat16 hb = __float2bfloat16(hp[k0 + j]);
            ah[kk][j] = *(const short*)&hb;
        }
    }

    floatx4 ai[12] = {}, ahh[12] = {};
    #pragma unroll
    for (int nb = 0; nb < 12; ++nb) {
        #pragma unroll
        for (int kk = 0; kk < 2; ++kk) {
            #pragma unroll
            for (int part = 0; part < 2; ++part) {
                const short8 bi = *(const short8*)(gwp + (size_t)(((0 * 12 + nb) * 2 + kk) * 2 + part) * 512 + lane * 8);
                ai[nb] = __builtin_amdgcn_mfma_f32_16x16x32_bf16(am[kk], bi, ai[nb], 0, 0, 0);
                const short8 bh = *(const short8*)(gwp + (size_t)(((1 * 12 + nb) * 2 + kk) * 2 + part) * 512 + lane * 8);
                ahh[nb] = __builtin_amdgcn_mfma_f32_16x16x32_bf16(ah[kk], bh, ahh[nb], 0, 0, 0);
            }
        }
    }

    #pragma unroll
    for (int f = 0; f < 4; ++f) {
        const int d = f * 16 + lr;
        const float bir = b_ih[d],       bhr = b_hh[d];
        const float biz = b_ih[64 + d],  bhz = b_hh[64 + d];
        const float bin = b_ih[128 + d], bhn = b_hh[128 + d];
        #pragma unroll
        for (int r = 0; r < 4; ++r) {
            const int row = wnb0 + quad * 4 + r;
            const float rr = sigm(ai[f][r] + bir + ahh[f][r] + bhr);
            const float zz = sigm(ai[f + 4][r] + biz + ahh[f + 4][r] + bhz);
            const float nn = tanhf(ai[f + 8][r] + bin + rr * (ahh[f + 8][r] + bhn));
            const float hd = out[(size_t)row * 64 + d];
            out[(size_t)row * 64 + d] = (1.0f - zz) * nn + zz * hd;
        }
    }
}

// FUSED Set2Set: all 3 processing steps in ONE launch.
__global__ __launch_bounds__(256) void k5_fused(float* __restrict__ qstar,
                                                const float* __restrict__ w_ih,
                                                const float* __restrict__ w_hh,
                                                const float* __restrict__ b_ih,
                                                const float* __restrict__ b_hh,
                                                const float* __restrict__ out,
                                                const int* __restrict__ rowptr) {
    const int g = blockIdx.x;
    const int j = threadIdx.x;
    __shared__ float qs[128], hv[64], gates[256];
    __shared__ float smw[4], sSw[4], srw[4][64];
    if (j < 128) qs[j] = 0.0f;
    if (j < 64) hv[j] = 0.0f;
    float creg = 0.0f;               // cs state (threads j<64)
    const int wv = j >> 6, lane = j & 63;
    const int start = rowptr[g], end = rowptr[g + 1];
    const float bsum = b_ih[j] + b_hh[j];

    for (int step = 0; step < 3; ++step) {
        __syncthreads();             // qs/hv (and smw/srw reuse) ready
        float acc = bsum;
        for (int k4 = 0; k4 < 128; k4 += 4) {
            float4 v = *(const float4*)(w_ih + (size_t)j * 128 + k4);
            const float* pv = (const float*)&v;
            #pragma unroll
            for (int t = 0; t < 4; ++t) acc += qs[k4 + t] * pv[t];
        }
        for (int k4 = 0; k4 < 64; k4 += 4) {
            float4 v = *(const float4*)(w_hh + (size_t)j * 64 + k4);
            const float* pv = (const float*)&v;
            #pragma unroll
            for (int t = 0; t < 4; ++t) acc += hv[k4 + t] * pv[t];
        }
        gates[j] = acc;
        __syncthreads();
        if (j < 64) {
            const float ig = sigm(gates[j]);
            const float fg = sigm(gates[64 + j]);
            const float gg = tanhf(gates[128 + j]);
            const float og = sigm(gates[192 + j]);
            creg = fg * creg + ig * gg;
            const float h = og * tanhf(creg);
            hv[j] = h;
            qs[j] = h;
        }
        __syncthreads();
        // attention: wave wv handles nodes start+wv, start+wv+4, ...
        const float q = hv[lane];
        float m = -3.4e38f, S = 0.0f, racc = 0.0f;
        for (int n = start + wv; n < end; n += 4) {
            const float ov = out[(size_t)n * 64 + lane];
            float p = ov * q;
            #pragma unroll
            for (int off = 1; off < 64; off <<= 1) p += __shfl_xor(p, off);
            if (p > m) {
                const float sc = __expf(m - p);
                S = S * sc + 1.0f;
                racc = racc * sc + ov;
                m = p;
            } else {
                const float w = __expf(p - m);
                S += w;
                racc += w * ov;
            }
        }
        if (lane == 0) { smw[wv] = m; sSw[wv] = S; }
        srw[wv][lane] = racc;
        __syncthreads();
        if (wv == 0) {
            const float mstar = fmaxf(fmaxf(smw[0], smw[1]), fmaxf(smw[2], smw[3]));
            float Ssum = 0.0f, rsum = 0.0f;
            #pragma unroll
            for (int i = 0; i < 4; ++i) {
                const float sc = __expf(smw[i] - mstar);   // empty wave: exp(-huge)=0
                Ssum += sSw[i] * sc;
                rsum += srw[i][lane] * sc;
            }
            qs[64 + lane] = rsum / (Ssum + 1e-16f);
        }
    }
    __syncthreads();
    if (j < 128) qstar[(size_t)g * 128 + j] = qs[j];
}

__global__ void k_out(const float* __restrict__ qstar, const float* __restrict__ outb,
                      float* __restrict__ dst, int nq, int nfeat, int out_n) {
    int i = blockIdx.x * 256 + threadIdx.x;
    if (i >= out_n) return;
    float v = 0.0f;
    if (i < nq) v = qstar[i];
    else if (i - nq < nfeat) v = outb[i - nq];
    dst[i] = v;
}

extern "C" void kernel_launch(void* const* d_in, const int* in_sizes, int n_in,
                              void* d_out, int out_size, void* d_ws, size_t ws_size,
                              hipStream_t stream) {
    constexpr int N = GN, E = GE, B = GB;

    char* ws = (char*)d_ws;
    size_t off = 0;
    auto alloc = [&](size_t bytes) { size_t o = off; off = (off + bytes + 255) & ~(size_t)255; return o; };

    int*   fl     = (int*)  (ws + alloc(19 * 4));
    int*   flagE  = (int*)  (ws + alloc(256));
    int*   flagG  = (int*)  (ws + alloc(256));
    float* counts = (float*)(ws + alloc((size_t)N * 4));
    int*   rowptr = (int*)  (ws + alloc((size_t)(B + 1) * 4));
    float* outbuf = (float*)(ws + alloc((size_t)N * 64 * 4));
    float* agg    = (float*)(ws + alloc((size_t)N * 64 * 4));
    float* qstar  = (float*)(ws + alloc((size_t)B * 128 * 4));
    __hip_bfloat16* h1  = (__hip_bfloat16*)(ws + alloc((size_t)E * 128 * 2));
    __hip_bfloat16* w2P = (__hip_bfloat16*)(ws + alloc((size_t)4096 * 128 * 2));
    __hip_bfloat16* gwp = (__hip_bfloat16*)(ws + alloc((size_t)2 * 12 * 2 * 2 * 512 * 2));

    const int fidx[15]  = {4, 5, 6, 7, 8, 9, 10, 11, 12, 13, 14, 15, 16, 17, 18};
    const int fsize[15] = {75 * 64, 64, 16 * 128, 128, 128 * 4096, 4096, 64,
                           192 * 64, 192 * 64, 192, 192, 256 * 128, 256 * 64, 256, 256};
    float* F[19] = {};
    for (int t = 0; t < 15; ++t) F[fidx[t]] = (float*)(ws + alloc((size_t)fsize[t] * 4));

    DetectArgs da;
    da.src[0] = d_in[0]; da.nhalf[0] = N * 75; da.fi[0] = 0;
    da.src[1] = d_in[1]; da.nhalf[1] = E * 16; da.fi[1] = 1;
    for (int t = 0; t < 15; ++t) { da.src[2 + t] = d_in[fidx[t]]; da.nhalf[2 + t] = fsize[t]; da.fi[2 + t] = fidx[t]; }
    k_detect<<<19, 256, 0, stream>>>(da, (const unsigned int*)d_in[2],
                                     (const unsigned int*)d_in[3], fl, flagE, flagG);

    CvtArgs ca;
    int pre = 0;
    for (int t = 0; t < 15; ++t) {
        ca.src[t] = d_in[fidx[t]]; ca.dst[t] = F[fidx[t]]; ca.n[t] = fsize[t]; ca.fi[t] = fidx[t];
        ca.pre[t] = pre; pre += (fsize[t] + 255) / 256;
    }
    ca.pre[15] = pre;
    k_cvt_all<<<pre, 256, 0, stream>>>(ca, fl);
    k_t2<<<256, 256, 0, stream>>>(d_in[8], w2P, fl + 8);
    k_gpack2<<<12, 256, 0, stream>>>(F[11], F[12], gwp);

    hipMemsetAsync(counts, 0, (size_t)N * 4, stream);
    hipMemsetAsync(qstar, 0, (size_t)B * 128 * 4, stream);

    k_counts<<<E / 256, 256, 0, stream>>>(d_in[2], flagE, counts, E);
    k_rowptr<<<(B + 1 + 255) / 256, 256, 0, stream>>>(d_in[3], flagG, rowptr, N, B);
    k_lin0<<<N / 4, 256, 0, stream>>>(d_in[0], F[4], F[5], outbuf, fl + 0);
    k1_h1<<<E / 2, 256, 0, stream>>>(d_in[1], F[6], F[7], h1, fl + 1);

    for (int it = 0; it < 3; ++it) {
        hipMemsetAsync(agg, 0, (size_t)N * 64 * 4, stream);
        k23_fused<<<E / 64, 256, 0, stream>>>(h1, w2P, F[9], outbuf, d_in[2], flagE, agg);
        k4_gru<<<N / 64, 256, 0, stream>>>(agg, counts, F[10], gwp, F[13], F[14], outbuf);
    }
    k5_fused<<<B, 256, 0, stream>>>(qstar, F[15], F[16], F[17], F[18], outbuf, rowptr);
    k_out<<<(out_size + 255) / 256, 256, 0, stream>>>(qstar, outbuf, (float*)d_out,
                                                      B * 128, N * 64, out_size);
}

// Round 10
// 970.877 us; speedup vs baseline: 1.8781x; 1.0018x over previous
//
#include <hip/hip_runtime.h>
#include <hip/hip_bf16.h>

#define GN 65536
#define GE 131072
#define GB 2048

typedef __attribute__((ext_vector_type(8))) short short8;
typedef __attribute__((ext_vector_type(4))) float floatx4;

static __device__ __forceinline__ float sigm(float x) { return 1.0f / (1.0f + __expf(-x)); }
static __device__ __forceinline__ float bf2f(unsigned short u) {
    union { unsigned int i; float f; } v; v.i = ((unsigned int)u) << 16; return v.f;
}
static __device__ __forceinline__ int geti(const void* p, long long i, int f64) {
    return f64 ? (int)((const long long*)p)[i] : ((const int*)p)[i];
}

// ---- merged detectors: blocks 0-16 float-dtype, 17 edge-i64, 18 graph-i64 ----
struct DetectArgs { const void* src[17]; int nhalf[17]; int fi[17]; };
__global__ void k_detect(DetectArgs a, const unsigned int* __restrict__ pe,
                         const unsigned int* __restrict__ pg,
                         int* __restrict__ flags, int* __restrict__ flagE,
                         int* __restrict__ flagG) {
    __shared__ unsigned int sA[256], sB[256];
    if (blockIdx.x >= 17) {
        const unsigned int* p = (blockIdx.x == 17) ? pe : pg;
        const long long nwords = (blockIdx.x == 17) ? (long long)2 * GE : (long long)GN;
        const long long lim = nwords < 16384 ? nwords : 16384;
        unsigned int acc = 0;
        for (long long w = 1 + 2 * (long long)threadIdx.x; w < lim; w += 512) acc |= p[w];
        sA[threadIdx.x] = acc;
        __syncthreads();
        for (int st = 128; st > 0; st >>= 1) {
            if (threadIdx.x < st) sA[threadIdx.x] |= sA[threadIdx.x + st];
            __syncthreads();
        }
        if (threadIdx.x == 0) *((blockIdx.x == 17) ? flagE : flagG) = (sA[0] == 0u) ? 1 : 0;
        return;
    }
    const unsigned short* p = (const unsigned short*)a.src[blockIdx.x];
    const int n0 = a.nhalf[blockIdx.x];
    const int n = n0 < 16384 ? n0 : 16384;
    unsigned int any = 0, orEven = 0;
    for (int i = threadIdx.x; i < n; i += 256) {
        const unsigned short u = p[i];
        const float av = fabsf(bf2f(u));
        if (!(av <= 1e6f)) any = 1u;
        if ((i & 1) == 0) orEven |= u;
    }
    sA[threadIdx.x] = any; sB[threadIdx.x] = orEven;
    __syncthreads();
    for (int s = 128; s > 0; s >>= 1) {
        if (threadIdx.x < s) {
            sA[threadIdx.x] |= sA[threadIdx.x + s];
            sB[threadIdx.x] |= sB[threadIdx.x + s];
        }
        __syncthreads();
    }
    if (threadIdx.x == 0) flags[a.fi[blockIdx.x]] = (sA[0] || sB[0] == 0u) ? 1 : 0;
}

// ---- batched f32 canonicalization of the 15 small float tensors ----
struct CvtArgs { const void* src[15]; float* dst[15]; int n[15]; int fi[15]; int pre[16]; };
__global__ void k_cvt_all(CvtArgs a, const int* __restrict__ flags) {
    const int b = blockIdx.x;
    int t = 0;
    while (t < 14 && b >= a.pre[t + 1]) ++t;
    const int i = (b - a.pre[t]) * 256 + threadIdx.x;
    if (i >= a.n[t]) return;
    const int f = flags[a.fi[t]];
    a.dst[t][i] = f ? ((const float*)a.src[t])[i] : bf2f(((const unsigned short*)a.src[t])[i]);
}

// repack w2 [128][4096] -> w2P bf16, COALESCED-FRAGMENT layout:
// group g = ((t*4 + kk)*8 + rb); each wave fragment load is one contiguous 1KB segment.
__global__ __launch_bounds__(256) void k_t2(const void* __restrict__ src,
                                            __hip_bfloat16* __restrict__ w2P,
                                            const int* __restrict__ flag) {
    const int tid8 = blockIdx.x * 256 + threadIdx.x;   // 65536 producers of 8 elems
    const int quad = tid8 & 3, lr = (tid8 >> 2) & 15, rb = (tid8 >> 6) & 7,
              kk = (tid8 >> 9) & 3, t = tid8 >> 11;
    const int n = t * 128 + rb * 16 + lr;              // output col 0..4095
    const int k0 = kk * 32 + quad * 8;                 // k 0..127
    const int isf32 = *flag;
    short8 v;
    #pragma unroll
    for (int j = 0; j < 8; ++j) {
        const size_t si = (size_t)(k0 + j) * 4096 + n;
        const float f = isf32 ? ((const float*)src)[si] : bf2f(((const unsigned short*)src)[si]);
        const __hip_bfloat16 b = __float2bfloat16(f);
        v[j] = *(const short*)&b;
    }
    *(short8*)(w2P + (size_t)tid8 * 8) = v;
}

// pack GRU weights into MFMA B-fragment layout, hi/lo bf16 split.
__global__ void k_gpack2(const float* __restrict__ w_ih, const float* __restrict__ w_hh,
                         __hip_bfloat16* __restrict__ gwp) {
    const int t = blockIdx.x * 256 + threadIdx.x;
    if (t >= 3072) return;
    const int lane = t & 63;
    const int kk = (t >> 6) & 1;
    const int nb = (t >> 7) % 12;
    const int mat = t / 1536;
    const float* W = mat ? w_hh : w_ih;          // [192][64]
    const int c = nb * 16 + (lane & 15);
    const int k0 = kk * 32 + (lane >> 4) * 8;
    short8 hi, lo;
    #pragma unroll
    for (int j = 0; j < 8; ++j) {
        const float v = W[c * 64 + k0 + j];
        const __hip_bfloat16 bh = __float2bfloat16(v);
        hi[j] = *(const short*)&bh;
        const __hip_bfloat16 bl = __float2bfloat16(v - __bfloat162float(bh));
        lo[j] = *(const short*)&bl;
    }
    const size_t base = (size_t)(((mat * 12 + nb) * 2 + kk) * 2);
    *(short8*)(gwp + (base + 0) * 512 + lane * 8) = hi;
    *(short8*)(gwp + (base + 1) * 512 + lane * 8) = lo;
}

__global__ void k_counts(const void* __restrict__ eidx, const int* __restrict__ fi64,
                         float* __restrict__ counts, int E_) {
    int e = blockIdx.x * 256 + threadIdx.x;
    if (e < E_) atomicAdd(&counts[geti(eidx, (long long)E_ + e, *fi64)], 1.0f);
}

__global__ void k_rowptr(const void* __restrict__ gi, const int* __restrict__ fi64,
                         int* __restrict__ rowptr, int N_, int B_) {
    int g = blockIdx.x * 256 + threadIdx.x;
    if (g > B_) return;
    const int f64 = *fi64;
    int lo = 0, hi = N_;
    while (lo < hi) { int mid = (lo + hi) >> 1; if (geti(gi, mid, f64) < g) lo = mid + 1; else hi = mid; }
    rowptr[g] = lo;
}

// lin0: out = relu(nf @ lin0_w + b)
__global__ __launch_bounds__(256) void k_lin0(const void* __restrict__ nf_raw,
                                              const float* __restrict__ w,
                                              const float* __restrict__ b,
                                              float* __restrict__ out,
                                              const int* __restrict__ flag) {
    const int ln = threadIdx.x >> 6;
    const int d = threadIdx.x & 63;
    const int n = blockIdx.x * 4 + ln;
    const int isf32 = *flag;
    __shared__ float s_nf[4][76];
    const size_t base = (size_t)n * 75;
    s_nf[ln][d] = isf32 ? ((const float*)nf_raw)[base + d] : bf2f(((const unsigned short*)nf_raw)[base + d]);
    if (d < 11) s_nf[ln][64 + d] = isf32 ? ((const float*)nf_raw)[base + 64 + d]
                                         : bf2f(((const unsigned short*)nf_raw)[base + 64 + d]);
    __syncthreads();
    float acc = b[d];
    #pragma unroll
    for (int i = 0; i < 75; ++i) acc += s_nf[ln][i] * w[i * 64 + d];
    out[(size_t)n * 64 + d] = fmaxf(acc, 0.0f);
}

// h1 = relu(ef @ w1 + b1) -> bf16 in MFMA FRAGMENT-SEGMENT layout:
// h1P[eb*8192 + (kk*4+rb)*512 + lane*8 + j], eb = e>>6, rb = (e&63)>>4,
// lane = ((col>>3)&3)*16 + (e&15), kk = col>>5, j = col&7.
// => k23's A-stage is a flat 16KB copy and A ds_reads are lane-consecutive
// (zero bank conflicts; r9's XOR layout still had 8-way on A-reads = 1.8e7).
__global__ __launch_bounds__(256) void k1_h1(const void* __restrict__ ef_raw,
                                             const float* __restrict__ w1,
                                             const float* __restrict__ b1,
                                             __hip_bfloat16* __restrict__ h1P,
                                             const int* __restrict__ flag) {
    const int le = threadIdx.x >> 7;
    const int j = threadIdx.x & 127;
    const int e = blockIdx.x * 2 + le;
    const int isf32 = *flag;
    __shared__ float efs[2][16];
    if (j < 16) {
        const size_t idx = (size_t)e * 16 + j;
        efs[le][j] = isf32 ? ((const float*)ef_raw)[idx] : bf2f(((const unsigned short*)ef_raw)[idx]);
    }
    __syncthreads();
    float acc = b1[j];
    #pragma unroll
    for (int i = 0; i < 16; ++i) acc += efs[le][i] * w1[i * 128 + j];
    const int eb = e >> 6, er = e & 63, rb = er >> 4, lre = er & 15;
    const int kk = j >> 5, qd = (j >> 3) & 3, jj = j & 7;
    h1P[(size_t)eb * 8192 + (kk * 4 + rb) * 512 + (qd * 16 + lre) * 8 + jj] =
        __float2bfloat16(fmaxf(acc, 0.0f));
}

// FUSED NNConv v11: r9 structure (4-wave blocks, 64 edges, B dbuf regs,
// LDS-merged atomics) + A in FRAGMENT-SEGMENT LDS layout: each a-fragment is
// one contiguous 1KB segment, ds_read_b128 at base+lane*16+const-offset ->
// zero bank conflicts (r9: 1.8e7 = ~70kcy/CU), offsets fold into ds_read
// immediates (less addr VALU/VGPR).
__global__ __launch_bounds__(256) void k23_fused(const __hip_bfloat16* __restrict__ h1P,
                                                 const __hip_bfloat16* __restrict__ w2P,
                                                 const float* __restrict__ b2,
                                                 const float* __restrict__ out,
                                                 const void* __restrict__ eidx,
                                                 const int* __restrict__ fi64,
                                                 float* __restrict__ agg) {
    __shared__ __align__(16) __hip_bfloat16 As[64 * 128];   // 16 KB; aliased as merge buf
    __shared__ float yT[64][65];                            // 16.6 KB [d][e]
    __shared__ int sdx[64];                                 // dst indices
    const int tid = threadIdx.x;
    const int e0 = blockIdx.x * 64;
    const int f64 = *fi64;

    const int wave = tid >> 6, lane = tid & 63;
    const int wn = wave * 32;              // 4 N-slices of 32 cols
    const int lr = lane & 15, quad = lane >> 4;

    if (tid < 64) sdx[tid] = geti(eidx, (long long)GE + e0 + tid, f64);
    // stage As: flat 16KB coalesced copy (h1P is already the LDS image)
    {
        const short8* s8 = (const short8*)(h1P + (size_t)blockIdx.x * 8192);
        short8* d8 = (short8*)As;
        #pragma unroll
        for (int i = 0; i < 4; ++i) d8[i * 256 + tid] = s8[i * 256 + tid];
    }
    // stage yT[d][e] = out[src[e]][d]
    {
        const int e = tid >> 2, d0 = (tid & 3) * 16;
        const int s = geti(eidx, e0 + e, f64);
        const float* srow = out + (size_t)s * 64 + d0;
        #pragma unroll
        for (int j = 0; j < 4; ++j) {
            float4 v = *(const float4*)(srow + j * 4);
            yT[d0 + j * 4 + 0][e] = v.x;
            yT[d0 + j * 4 + 1][e] = v.y;
            yT[d0 + j * 4 + 2][e] = v.z;
            yT[d0 + j * 4 + 3][e] = v.w;
        }
    }
    __syncthreads();

    const int lin = (lr * 4 + quad) * 8;   // lane offset inside a 512-elem group
    const char* Ab = (const char*)As + lane * 16;   // lane-consecutive A base
    float msum[4][2][4] = {};

#define K23_LOADB(dst, tt)                                                      \
    _Pragma("unroll")                                                           \
    for (int kk = 0; kk < 4; ++kk) {                                            \
        _Pragma("unroll")                                                       \
        for (int nt = 0; nt < 2; ++nt) {                                        \
            const int g = ((tt) * 4 + kk) * 8 + (wn >> 4) + nt;                 \
            dst[kk][nt] = *(const short8*)(w2P + (size_t)g * 512 + lin);        \
        }                                                                       \
    }                                                                           \
    __builtin_amdgcn_sched_barrier(0);

#define K23_BODY(tt, buf) {                                                     \
    const int n0 = (tt) * 128;                                                  \
    const int dcur = (n0 + wn) >> 6;                                            \
    const float b2v0 = b2[n0 + wn + lr];                                        \
    const float b2v1 = b2[n0 + wn + 16 + lr];                                   \
    floatx4 acc[4][2] = {};                                                     \
    _Pragma("unroll")                                                           \
    for (int kk = 0; kk < 4; ++kk) {                                            \
        short8 a0, a1, a2, a3;                                                  \
        a0 = *(const short8*)(Ab + kk * 4096 + 0 * 1024);                       \
        a1 = *(const short8*)(Ab + kk * 4096 + 1 * 1024);                       \
        a2 = *(const short8*)(Ab + kk * 4096 + 2 * 1024);                       \
        a3 = *(const short8*)(Ab + kk * 4096 + 3 * 1024);                       \
        __builtin_amdgcn_s_setprio(1);                                          \
        acc[0][0] = __builtin_amdgcn_mfma_f32_16x16x32_bf16(a0, buf[kk][0], acc[0][0], 0, 0, 0); \
        acc[0][1] = __builtin_amdgcn_mfma_f32_16x16x32_bf16(a0, buf[kk][1], acc[0][1], 0, 0, 0); \
        acc[1][0] = __builtin_amdgcn_mfma_f32_16x16x32_bf16(a1, buf[kk][0], acc[1][0], 0, 0, 0); \
        acc[1][1] = __builtin_amdgcn_mfma_f32_16x16x32_bf16(a1, buf[kk][1], acc[1][1], 0, 0, 0); \
        acc[2][0] = __builtin_amdgcn_mfma_f32_16x16x32_bf16(a2, buf[kk][0], acc[2][0], 0, 0, 0); \
        acc[2][1] = __builtin_amdgcn_mfma_f32_16x16x32_bf16(a2, buf[kk][1], acc[2][1], 0, 0, 0); \
        acc[3][0] = __builtin_amdgcn_mfma_f32_16x16x32_bf16(a3, buf[kk][0], acc[3][0], 0, 0, 0); \
        acc[3][1] = __builtin_amdgcn_mfma_f32_16x16x32_bf16(a3, buf[kk][1], acc[3][1], 0, 0, 0); \
        __builtin_amdgcn_s_setprio(0);                                          \
    }                                                                           \
    _Pragma("unroll")                                                           \
    for (int mt = 0; mt < 4; ++mt) {                                            \
        _Pragma("unroll")                                                       \
        for (int r = 0; r < 4; ++r) {                                           \
            const float yv = yT[dcur][mt * 16 + quad * 4 + r];                  \
            msum[mt][0][r] = fmaf(yv, acc[mt][0][r] + b2v0, msum[mt][0][r]);    \
            msum[mt][1][r] = fmaf(yv, acc[mt][1][r] + b2v1, msum[mt][1][r]);    \
        }                                                                       \
    }                                                                           \
}

    short8 bA[4][2], bB[4][2];
    K23_LOADB(bA, 0)
    #pragma unroll 1
    for (int t = 0; t < 32; t += 2) {
        K23_LOADB(bB, t + 1)          // in flight across BODY(t)
        K23_BODY(t, bA)
        if (t + 2 < 32) { K23_LOADB(bA, t + 2) }  // in flight across BODY(t+1)
        K23_BODY(t + 1, bB)
    }
#undef K23_LOADB
#undef K23_BODY

    // merged epilogue: fold wave-pair (wn, wn+64) partials in LDS, then
    // one coalesced atomicAdd set. As (16KB) aliased as 64x64 f32 merge buf.
    __syncthreads();                       // all waves done with As/yT
    float* mg = (float*)As;
    const int fb = (wn & 32);
    if (wave < 2) {
        #pragma unroll
        for (int mt = 0; mt < 4; ++mt)
            #pragma unroll
            for (int r = 0; r < 4; ++r)
                #pragma unroll
                for (int nt = 0; nt < 2; ++nt)
                    mg[(mt * 16 + quad * 4 + r) * 64 + fb + nt * 16 + lr] = msum[mt][nt][r];
    }
    __syncthreads();
    if (wave >= 2) {
        #pragma unroll
        for (int mt = 0; mt < 4; ++mt)
            #pragma unroll
            for (int r = 0; r < 4; ++r)
                #pragma unroll
                for (int nt = 0; nt < 2; ++nt)
                    mg[(mt * 16 + quad * 4 + r) * 64 + fb + nt * 16 + lr] += msum[mt][nt][r];
    }
    __syncthreads();
    #pragma unroll
    for (int i = 0; i < 16; ++i) {
        const int o = i * 256 + tid;
        const int row = o >> 6, col = o & 63;
        atomicAdd(&agg[(size_t)sdx[row] * 64 + col], mg[o]);
    }
}

// GRU v4: MFMA gate GEMMs (r7-verified).
__global__ __launch_bounds__(256) void k4_gru(const float* __restrict__ agg,
                                              const float* __restrict__ counts,
                                              const float* __restrict__ cbias,
                                              const __hip_bfloat16* __restrict__ gwp,
                                              const float* __restrict__ b_ih,
                                              const float* __restrict__ b_hh,
                                              float* __restrict__ out) {
    const int wv = threadIdx.x >> 6, lane = threadIdx.x & 63;
    const int lr = lane & 15, quad = lane >> 4;
    const int wnb0 = blockIdx.x * 64 + wv * 16;
    const int node = wnb0 + lr;

    const float rcnt = 1.0f / fmaxf(counts[node], 1.0f);
    const float* ap = agg + (size_t)node * 64;
    const float* hp = out + (size_t)node * 64;
    short8 am[2], ah[2];
    #pragma unroll
    for (int kk = 0; kk < 2; ++kk) {
        const int k0 = kk * 32 + quad * 8;
        #pragma unroll
        for (int j = 0; j < 8; ++j) {
            const float mv = fmaxf(ap[k0 + j] * rcnt + cbias[k0 + j], 0.0f);
            const __hip_bfloat16 mb = __float2bfloat16(mv);
            am[kk][j] = *(const short*)&mb;
            const __hip_bfloat16 hb = __float2bfloat16(hp[k0 + j]);
            ah[kk][j] = *(const short*)&hb;
        }
    }

    floatx4 ai[12] = {}, ahh[12] = {};
    #pragma unroll
    for (int nb = 0; nb < 12; ++nb) {
        #pragma unroll
        for (int kk = 0; kk < 2; ++kk) {
            #pragma unroll
            for (int part = 0; part < 2; ++part) {
                const short8 bi = *(const short8*)(gwp + (size_t)(((0 * 12 + nb) * 2 + kk) * 2 + part) * 512 + lane * 8);
                ai[nb] = __builtin_amdgcn_mfma_f32_16x16x32_bf16(am[kk], bi, ai[nb], 0, 0, 0);
                const short8 bh = *(const short8*)(gwp + (size_t)(((1 * 12 + nb) * 2 + kk) * 2 + part) * 512 + lane * 8);
                ahh[nb] = __builtin_amdgcn_mfma_f32_16x16x32_bf16(ah[kk], bh, ahh[nb], 0, 0, 0);
            }
        }
    }

    #pragma unroll
    for (int f = 0; f < 4; ++f) {
        const int d = f * 16 + lr;
        const float bir = b_ih[d],       bhr = b_hh[d];
        const float biz = b_ih[64 + d],  bhz = b_hh[64 + d];
        const float bin = b_ih[128 + d], bhn = b_hh[128 + d];
        #pragma unroll
        for (int r = 0; r < 4; ++r) {
            const int row = wnb0 + quad * 4 + r;
            const float rr = sigm(ai[f][r] + bir + ahh[f][r] + bhr);
            const float zz = sigm(ai[f + 4][r] + biz + ahh[f + 4][r] + bhz);
            const float nn = tanhf(ai[f + 8][r] + bin + rr * (ahh[f + 8][r] + bhn));
            const float hd = out[(size_t)row * 64 + d];
            out[(size_t)row * 64 + d] = (1.0f - zz) * nn + zz * hd;
        }
    }
}

// FUSED Set2Set: all 3 processing steps in ONE launch.
__global__ __launch_bounds__(256) void k5_fused(float* __restrict__ qstar,
                                                const float* __restrict__ w_ih,
                                                const float* __restrict__ w_hh,
                                                const float* __restrict__ b_ih,
                                                const float* __restrict__ b_hh,
                                                const float* __restrict__ out,
                                                const int* __restrict__ rowptr) {
    const int g = blockIdx.x;
    const int j = threadIdx.x;
    __shared__ float qs[128], hv[64], gates[256];
    __shared__ float smw[4], sSw[4], srw[4][64];
    if (j < 128) qs[j] = 0.0f;
    if (j < 64) hv[j] = 0.0f;
    float creg = 0.0f;               // cs state (threads j<64)
    const int wv = j >> 6, lane = j & 63;
    const int start = rowptr[g], end = rowptr[g + 1];
    const float bsum = b_ih[j] + b_hh[j];

    for (int step = 0; step < 3; ++step) {
        __syncthreads();             // qs/hv (and smw/srw reuse) ready
        float acc = bsum;
        for (int k4 = 0; k4 < 128; k4 += 4) {
            float4 v = *(const float4*)(w_ih + (size_t)j * 128 + k4);
            const float* pv = (const float*)&v;
            #pragma unroll
            for (int t = 0; t < 4; ++t) acc += qs[k4 + t] * pv[t];
        }
        for (int k4 = 0; k4 < 64; k4 += 4) {
            float4 v = *(const float4*)(w_hh + (size_t)j * 64 + k4);
            const float* pv = (const float*)&v;
            #pragma unroll
            for (int t = 0; t < 4; ++t) acc += hv[k4 + t] * pv[t];
        }
        gates[j] = acc;
        __syncthreads();
        if (j < 64) {
            const float ig = sigm(gates[j]);
            const float fg = sigm(gates[64 + j]);
            const float gg = tanhf(gates[128 + j]);
            const float og = sigm(gates[192 + j]);
            creg = fg * creg + ig * gg;
            const float h = og * tanhf(creg);
            hv[j] = h;
            qs[j] = h;
        }
        __syncthreads();
        // attention: wave wv handles nodes start+wv, start+wv+4, ...
        const float q = hv[lane];
        float m = -3.4e38f, S = 0.0f, racc = 0.0f;
        for (int n = start + wv; n < end; n += 4) {
            const float ov = out[(size_t)n * 64 + lane];
            float p = ov * q;
            #pragma unroll
            for (int off = 1; off < 64; off <<= 1) p += __shfl_xor(p, off);
            if (p > m) {
                const float sc = __expf(m - p);
                S = S * sc + 1.0f;
                racc = racc * sc + ov;
                m = p;
            } else {
                const float w = __expf(p - m);
                S += w;
                racc += w * ov;
            }
        }
        if (lane == 0) { smw[wv] = m; sSw[wv] = S; }
        srw[wv][lane] = racc;
        __syncthreads();
        if (wv == 0) {
            const float mstar = fmaxf(fmaxf(smw[0], smw[1]), fmaxf(smw[2], smw[3]));
            float Ssum = 0.0f, rsum = 0.0f;
            #pragma unroll
            for (int i = 0; i < 4; ++i) {
                const float sc = __expf(smw[i] - mstar);   // empty wave: exp(-huge)=0
                Ssum += sSw[i] * sc;
                rsum += srw[i][lane] * sc;
            }
            qs[64 + lane] = rsum / (Ssum + 1e-16f);
        }
    }
    __syncthreads();
    if (j < 128) qstar[(size_t)g * 128 + j] = qs[j];
}

__global__ void k_out(const float* __restrict__ qstar, const float* __restrict__ outb,
                      float* __restrict__ dst, int nq, int nfeat, int out_n) {
    int i = blockIdx.x * 256 + threadIdx.x;
    if (i >= out_n) return;
    float v = 0.0f;
    if (i < nq) v = qstar[i];
    else if (i - nq < nfeat) v = outb[i - nq];
    dst[i] = v;
}

extern "C" void kernel_launch(void* const* d_in, const int* in_sizes, int n_in,
                              void* d_out, int out_size, void* d_ws, size_t ws_size,
                              hipStream_t stream) {
    constexpr int N = GN, E = GE, B = GB;

    char* ws = (char*)d_ws;
    size_t off = 0;
    auto alloc = [&](size_t bytes) { size_t o = off; off = (off + bytes + 255) & ~(size_t)255; return o; };

    int*   fl     = (int*)  (ws + alloc(19 * 4));
    int*   flagE  = (int*)  (ws + alloc(256));
    int*   flagG  = (int*)  (ws + alloc(256));
    float* counts = (float*)(ws + alloc((size_t)N * 4));
    int*   rowptr = (int*)  (ws + alloc((size_t)(B + 1) * 4));
    float* outbuf = (float*)(ws + alloc((size_t)N * 64 * 4));
    float* agg    = (float*)(ws + alloc((size_t)N * 64 * 4));
    float* qstar  = (float*)(ws + alloc((size_t)B * 128 * 4));
    __hip_bfloat16* h1  = (__hip_bfloat16*)(ws + alloc((size_t)E * 128 * 2));
    __hip_bfloat16* w2P = (__hip_bfloat16*)(ws + alloc((size_t)4096 * 128 * 2));
    __hip_bfloat16* gwp = (__hip_bfloat16*)(ws + alloc((size_t)2 * 12 * 2 * 2 * 512 * 2));

    const int fidx[15]  = {4, 5, 6, 7, 8, 9, 10, 11, 12, 13, 14, 15, 16, 17, 18};
    const int fsize[15] = {75 * 64, 64, 16 * 128, 128, 128 * 4096, 4096, 64,
                           192 * 64, 192 * 64, 192, 192, 256 * 128, 256 * 64, 256, 256};
    float* F[19] = {};
    for (int t = 0; t < 15; ++t) F[fidx[t]] = (float*)(ws + alloc((size_t)fsize[t] * 4));

    DetectArgs da;
    da.src[0] = d_in[0]; da.nhalf[0] = N * 75; da.fi[0] = 0;
    da.src[1] = d_in[1]; da.nhalf[1] = E * 16; da.fi[1] = 1;
    for (int t = 0; t < 15; ++t) { da.src[2 + t] = d_in[fidx[t]]; da.nhalf[2 + t] = fsize[t]; da.fi[2 + t] = fidx[t]; }
    k_detect<<<19, 256, 0, stream>>>(da, (const unsigned int*)d_in[2],
                                     (const unsigned int*)d_in[3], fl, flagE, flagG);

    CvtArgs ca;
    int pre = 0;
    for (int t = 0; t < 15; ++t) {
        ca.src[t] = d_in[fidx[t]]; ca.dst[t] = F[fidx[t]]; ca.n[t] = fsize[t]; ca.fi[t] = fidx[t];
        ca.pre[t] = pre; pre += (fsize[t] + 255) / 256;
    }
    ca.pre[15] = pre;
    k_cvt_all<<<pre, 256, 0, stream>>>(ca, fl);
    k_t2<<<256, 256, 0, stream>>>(d_in[8], w2P, fl + 8);
    k_gpack2<<<12, 256, 0, stream>>>(F[11], F[12], gwp);

    hipMemsetAsync(counts, 0, (size_t)N * 4, stream);
    hipMemsetAsync(qstar, 0, (size_t)B * 128 * 4, stream);

    k_counts<<<E / 256, 256, 0, stream>>>(d_in[2], flagE, counts, E);
    k_rowptr<<<(B + 1 + 255) / 256, 256, 0, stream>>>(d_in[3], flagG, rowptr, N, B);
    k_lin0<<<N / 4, 256, 0, stream>>>(d_in[0], F[4], F[5], outbuf, fl + 0);
    k1_h1<<<E / 2, 256, 0, stream>>>(d_in[1], F[6], F[7], h1, fl + 1);

    for (int it = 0; it < 3; ++it) {
        hipMemsetAsync(agg, 0, (size_t)N * 64 * 4, stream);
        k23_fused<<<E / 64, 256, 0, stream>>>(h1, w2P, F[9], outbuf, d_in[2], flagE, agg);
        k4_gru<<<N / 64, 256, 0, stream>>>(agg, counts, F[10], gwp, F[13], F[14], outbuf);
    }
    k5_fused<<<B, 256, 0, stream>>>(qstar, F[15], F[16], F[17], F[18], outbuf, rowptr);
    k_out<<<(out_size + 255) / 256, 256, 0, stream>>>(qstar, outbuf, (float*)d_out,
                                                      B * 128, N * 64, out_size);
}

// Round 11
// 875.983 us; speedup vs baseline: 2.0815x; 1.1083x over previous
//
#include <hip/hip_runtime.h>
#include <hip/hip_bf16.h>

#define GN 65536
#define GE 131072
#define GB 2048

typedef __attribute__((ext_vector_type(8))) short short8;
typedef __attribute__((ext_vector_type(4))) float floatx4;

static __device__ __forceinline__ float sigm(float x) { return 1.0f / (1.0f + __expf(-x)); }
static __device__ __forceinline__ float bf2f(unsigned short u) {
    union { unsigned int i; float f; } v; v.i = ((unsigned int)u) << 16; return v.f;
}
static __device__ __forceinline__ int geti(const void* p, long long i, int f64) {
    return f64 ? (int)((const long long*)p)[i] : ((const int*)p)[i];
}

// ---- merged detectors: blocks 0-16 float-dtype, 17 edge-i64, 18 graph-i64 ----
struct DetectArgs { const void* src[17]; int nhalf[17]; int fi[17]; };
__global__ void k_detect(DetectArgs a, const unsigned int* __restrict__ pe,
                         const unsigned int* __restrict__ pg,
                         int* __restrict__ flags, int* __restrict__ flagE,
                         int* __restrict__ flagG) {
    __shared__ unsigned int sA[256], sB[256];
    if (blockIdx.x >= 17) {
        const unsigned int* p = (blockIdx.x == 17) ? pe : pg;
        const long long nwords = (blockIdx.x == 17) ? (long long)2 * GE : (long long)GN;
        const long long lim = nwords < 16384 ? nwords : 16384;
        unsigned int acc = 0;
        for (long long w = 1 + 2 * (long long)threadIdx.x; w < lim; w += 512) acc |= p[w];
        sA[threadIdx.x] = acc;
        __syncthreads();
        for (int st = 128; st > 0; st >>= 1) {
            if (threadIdx.x < st) sA[threadIdx.x] |= sA[threadIdx.x + st];
            __syncthreads();
        }
        if (threadIdx.x == 0) *((blockIdx.x == 17) ? flagE : flagG) = (sA[0] == 0u) ? 1 : 0;
        return;
    }
    const unsigned short* p = (const unsigned short*)a.src[blockIdx.x];
    const int n0 = a.nhalf[blockIdx.x];
    const int n = n0 < 16384 ? n0 : 16384;
    unsigned int any = 0, orEven = 0;
    for (int i = threadIdx.x; i < n; i += 256) {
        const unsigned short u = p[i];
        const float av = fabsf(bf2f(u));
        if (!(av <= 1e6f)) any = 1u;
        if ((i & 1) == 0) orEven |= u;
    }
    sA[threadIdx.x] = any; sB[threadIdx.x] = orEven;
    __syncthreads();
    for (int s = 128; s > 0; s >>= 1) {
        if (threadIdx.x < s) {
            sA[threadIdx.x] |= sA[threadIdx.x + s];
            sB[threadIdx.x] |= sB[threadIdx.x + s];
        }
        __syncthreads();
    }
    if (threadIdx.x == 0) flags[a.fi[blockIdx.x]] = (sA[0] || sB[0] == 0u) ? 1 : 0;
}

// ---- batched f32 canonicalization (14 tensors; dead w2->F[8] conversion dropped) ----
struct CvtArgs { const void* src[15]; float* dst[15]; int n[15]; int fi[15]; int pre[16]; };
__global__ void k_cvt_all(CvtArgs a, const int* __restrict__ flags) {
    const int b = blockIdx.x;
    int t = 0;
    while (t < 14 && b >= a.pre[t + 1]) ++t;
    const int i = (b - a.pre[t]) * 256 + threadIdx.x;
    if (i >= a.n[t]) return;
    const int f = flags[a.fi[t]];
    a.dst[t][i] = f ? ((const float*)a.src[t])[i] : bf2f(((const unsigned short*)a.src[t])[i]);
}

// repack w2 [128][4096] -> w2P bf16, COALESCED-FRAGMENT layout:
// group g = ((t*4 + kk)*8 + rb); each wave fragment load is one contiguous 1KB segment.
__global__ __launch_bounds__(256) void k_t2(const void* __restrict__ src,
                                            __hip_bfloat16* __restrict__ w2P,
                                            const int* __restrict__ flag) {
    const int tid8 = blockIdx.x * 256 + threadIdx.x;   // 65536 producers of 8 elems
    const int quad = tid8 & 3, lr = (tid8 >> 2) & 15, rb = (tid8 >> 6) & 7,
              kk = (tid8 >> 9) & 3, t = tid8 >> 11;
    const int n = t * 128 + rb * 16 + lr;              // output col 0..4095
    const int k0 = kk * 32 + quad * 8;                 // k 0..127
    const int isf32 = *flag;
    short8 v;
    #pragma unroll
    for (int j = 0; j < 8; ++j) {
        const size_t si = (size_t)(k0 + j) * 4096 + n;
        const float f = isf32 ? ((const float*)src)[si] : bf2f(((const unsigned short*)src)[si]);
        const __hip_bfloat16 b = __float2bfloat16(f);
        v[j] = *(const short*)&b;
    }
    *(short8*)(w2P + (size_t)tid8 * 8) = v;
}

// pack GRU weights into MFMA B-fragment layout, hi/lo bf16 split.
__global__ void k_gpack2(const float* __restrict__ w_ih, const float* __restrict__ w_hh,
                         __hip_bfloat16* __restrict__ gwp) {
    const int t = blockIdx.x * 256 + threadIdx.x;
    if (t >= 3072) return;
    const int lane = t & 63;
    const int kk = (t >> 6) & 1;
    const int nb = (t >> 7) % 12;
    const int mat = t / 1536;
    const float* W = mat ? w_hh : w_ih;          // [192][64]
    const int c = nb * 16 + (lane & 15);
    const int k0 = kk * 32 + (lane >> 4) * 8;
    short8 hi, lo;
    #pragma unroll
    for (int j = 0; j < 8; ++j) {
        const float v = W[c * 64 + k0 + j];
        const __hip_bfloat16 bh = __float2bfloat16(v);
        hi[j] = *(const short*)&bh;
        const __hip_bfloat16 bl = __float2bfloat16(v - __bfloat162float(bh));
        lo[j] = *(const short*)&bl;
    }
    const size_t base = (size_t)(((mat * 12 + nb) * 2 + kk) * 2);
    *(short8*)(gwp + (base + 0) * 512 + lane * 8) = hi;
    *(short8*)(gwp + (base + 1) * 512 + lane * 8) = lo;
}

// merged: blocks 0..511 = edge-count atomics; blocks 512+ = rowptr binary search
__global__ void k_cnt_rp(const void* __restrict__ eidx, const void* __restrict__ gi,
                         const int* __restrict__ flagE, const int* __restrict__ flagG,
                         float* __restrict__ counts, int* __restrict__ rowptr) {
    if (blockIdx.x < 512) {
        const int e = blockIdx.x * 256 + threadIdx.x;
        atomicAdd(&counts[geti(eidx, (long long)GE + e, *flagE)], 1.0f);
        return;
    }
    const int g = (blockIdx.x - 512) * 256 + threadIdx.x;
    if (g > GB) return;
    const int f64 = *flagG;
    int lo = 0, hi = GN;
    while (lo < hi) { int mid = (lo + hi) >> 1; if (geti(gi, mid, f64) < g) lo = mid + 1; else hi = mid; }
    rowptr[g] = lo;
}

// lin0: out = relu(nf @ lin0_w + b); 16 nodes/block, whole w staged in LDS
__global__ __launch_bounds__(256) void k_lin0(const void* __restrict__ nf_raw,
                                              const float* __restrict__ w,
                                              const float* __restrict__ b,
                                              float* __restrict__ out,
                                              const int* __restrict__ flag) {
    __shared__ float sw[75][66];
    __shared__ float snf[16][76];
    const int tid = threadIdx.x;
    const int isf32 = *flag;
    const int nb0 = blockIdx.x * 16;
    for (int i = tid; i < 75 * 64; i += 256) sw[i >> 6][i & 63] = w[i];
    for (int i = tid; i < 16 * 75; i += 256) {
        const int nn = i / 75, ii = i % 75;
        const size_t idx = (size_t)(nb0 + nn) * 75 + ii;
        snf[nn][ii] = isf32 ? ((const float*)nf_raw)[idx] : bf2f(((const unsigned short*)nf_raw)[idx]);
    }
    __syncthreads();
    const int ln = tid >> 6, d = tid & 63;
    const float bd = b[d];
    #pragma unroll
    for (int g = 0; g < 4; ++g) {
        const int nn = ln * 4 + g;
        float acc = bd;
        #pragma unroll
        for (int i = 0; i < 75; ++i) acc = fmaf(snf[nn][i], sw[i][d], acc);
        out[(size_t)(nb0 + nn) * 64 + d] = fmaxf(acc, 0.0f);
    }
}

// h1 = relu(ef @ w1 + b1) -> bf16 in MFMA FRAGMENT-SEGMENT layout (h1P).
// 16 edges/block: w1 column cached in regs, applied to 8 edges per thread
// (8x fewer blocks + 8x fewer w1 re-reads than the 2-edge version).
__global__ __launch_bounds__(256) void k1_h1(const void* __restrict__ ef_raw,
                                             const float* __restrict__ w1,
                                             const float* __restrict__ b1,
                                             __hip_bfloat16* __restrict__ h1P,
                                             const int* __restrict__ flag) {
    const int j = threadIdx.x & 127, half = threadIdx.x >> 7;
    const int eb0 = blockIdx.x * 16;
    const int isf32 = *flag;
    __shared__ float efs[16][17];
    {
        const int e = threadIdx.x >> 4, i = threadIdx.x & 15;
        const size_t idx = (size_t)(eb0 + e) * 16 + i;
        efs[e][i] = isf32 ? ((const float*)ef_raw)[idx] : bf2f(((const unsigned short*)ef_raw)[idx]);
    }
    __syncthreads();
    float wcol[16];
    #pragma unroll
    for (int i = 0; i < 16; ++i) wcol[i] = w1[i * 128 + j];
    const float bj = b1[j];
    const int kk = j >> 5, qd = (j >> 3) & 3, jj = j & 7;
    #pragma unroll
    for (int eo = 0; eo < 8; ++eo) {
        const int e = eb0 + half * 8 + eo;
        float acc = bj;
        #pragma unroll
        for (int i = 0; i < 16; ++i) acc = fmaf(efs[half * 8 + eo][i], wcol[i], acc);
        const int ebk = e >> 6, er = e & 63, rb = er >> 4, lre = er & 15;
        h1P[(size_t)ebk * 8192 + (kk * 4 + rb) * 512 + (qd * 16 + lre) * 8 + jj] =
            __float2bfloat16(fmaxf(acc, 0.0f));
    }
}

// FUSED NNConv v12: r10 structure + __launch_bounds__(256,3) occupancy probe
// (r10: all pipes <40% busy, latency-bound ds_read->MFMA chain at 2 waves/SIMD;
// reg arithmetic ~140/thread should admit 3 waves/SIMD).
__global__ __launch_bounds__(256, 3) void k23_fused(const __hip_bfloat16* __restrict__ h1P,
                                                 const __hip_bfloat16* __restrict__ w2P,
                                                 const float* __restrict__ b2,
                                                 const float* __restrict__ out,
                                                 const void* __restrict__ eidx,
                                                 const int* __restrict__ fi64,
                                                 float* __restrict__ agg) {
    __shared__ __align__(16) __hip_bfloat16 As[64 * 128];   // 16 KB; aliased as merge buf
    __shared__ float yT[64][65];                            // 16.6 KB [d][e]
    __shared__ int sdx[64];                                 // dst indices
    const int tid = threadIdx.x;
    const int e0 = blockIdx.x * 64;
    const int f64 = *fi64;

    const int wave = tid >> 6, lane = tid & 63;
    const int wn = wave * 32;              // 4 N-slices of 32 cols
    const int lr = lane & 15, quad = lane >> 4;

    if (tid < 64) sdx[tid] = geti(eidx, (long long)GE + e0 + tid, f64);
    // stage As: flat 16KB coalesced copy (h1P is already the LDS image)
    {
        const short8* s8 = (const short8*)(h1P + (size_t)blockIdx.x * 8192);
        short8* d8 = (short8*)As;
        #pragma unroll
        for (int i = 0; i < 4; ++i) d8[i * 256 + tid] = s8[i * 256 + tid];
    }
    // stage yT[d][e] = out[src[e]][d]
    {
        const int e = tid >> 2, d0 = (tid & 3) * 16;
        const int s = geti(eidx, e0 + e, f64);
        const float* srow = out + (size_t)s * 64 + d0;
        #pragma unroll
        for (int j = 0; j < 4; ++j) {
            float4 v = *(const float4*)(srow + j * 4);
            yT[d0 + j * 4 + 0][e] = v.x;
            yT[d0 + j * 4 + 1][e] = v.y;
            yT[d0 + j * 4 + 2][e] = v.z;
            yT[d0 + j * 4 + 3][e] = v.w;
        }
    }
    __syncthreads();

    const int lin = (lr * 4 + quad) * 8;   // lane offset inside a 512-elem group
    const char* Ab = (const char*)As + lane * 16;   // lane-consecutive A base
    float msum[4][2][4] = {};

#define K23_LOADB(dst, tt)                                                      \
    _Pragma("unroll")                                                           \
    for (int kk = 0; kk < 4; ++kk) {                                            \
        _Pragma("unroll")                                                       \
        for (int nt = 0; nt < 2; ++nt) {                                        \
            const int g = ((tt) * 4 + kk) * 8 + (wn >> 4) + nt;                 \
            dst[kk][nt] = *(const short8*)(w2P + (size_t)g * 512 + lin);        \
        }                                                                       \
    }                                                                           \
    __builtin_amdgcn_sched_barrier(0);

#define K23_BODY(tt, buf) {                                                     \
    const int n0 = (tt) * 128;                                                  \
    const int dcur = (n0 + wn) >> 6;                                            \
    const float b2v0 = b2[n0 + wn + lr];                                        \
    const float b2v1 = b2[n0 + wn + 16 + lr];                                   \
    floatx4 acc[4][2] = {};                                                     \
    _Pragma("unroll")                                                           \
    for (int kk = 0; kk < 4; ++kk) {                                            \
        short8 a0, a1, a2, a3;                                                  \
        a0 = *(const short8*)(Ab + kk * 4096 + 0 * 1024);                       \
        a1 = *(const short8*)(Ab + kk * 4096 + 1 * 1024);                       \
        a2 = *(const short8*)(Ab + kk * 4096 + 2 * 1024);                       \
        a3 = *(const short8*)(Ab + kk * 4096 + 3 * 1024);                       \
        __builtin_amdgcn_s_setprio(1);                                          \
        acc[0][0] = __builtin_amdgcn_mfma_f32_16x16x32_bf16(a0, buf[kk][0], acc[0][0], 0, 0, 0); \
        acc[0][1] = __builtin_amdgcn_mfma_f32_16x16x32_bf16(a0, buf[kk][1], acc[0][1], 0, 0, 0); \
        acc[1][0] = __builtin_amdgcn_mfma_f32_16x16x32_bf16(a1, buf[kk][0], acc[1][0], 0, 0, 0); \
        acc[1][1] = __builtin_amdgcn_mfma_f32_16x16x32_bf16(a1, buf[kk][1], acc[1][1], 0, 0, 0); \
        acc[2][0] = __builtin_amdgcn_mfma_f32_16x16x32_bf16(a2, buf[kk][0], acc[2][0], 0, 0, 0); \
        acc[2][1] = __builtin_amdgcn_mfma_f32_16x16x32_bf16(a2, buf[kk][1], acc[2][1], 0, 0, 0); \
        acc[3][0] = __builtin_amdgcn_mfma_f32_16x16x32_bf16(a3, buf[kk][0], acc[3][0], 0, 0, 0); \
        acc[3][1] = __builtin_amdgcn_mfma_f32_16x16x32_bf16(a3, buf[kk][1], acc[3][1], 0, 0, 0); \
        __builtin_amdgcn_s_setprio(0);                                          \
    }                                                                           \
    _Pragma("unroll")                                                           \
    for (int mt = 0; mt < 4; ++mt) {                                            \
        _Pragma("unroll")                                                       \
        for (int r = 0; r < 4; ++r) {                                           \
            const float yv = yT[dcur][mt * 16 + quad * 4 + r];                  \
            msum[mt][0][r] = fmaf(yv, acc[mt][0][r] + b2v0, msum[mt][0][r]);    \
            msum[mt][1][r] = fmaf(yv, acc[mt][1][r] + b2v1, msum[mt][1][r]);    \
        }                                                                       \
    }                                                                           \
}

    short8 bA[4][2], bB[4][2];
    K23_LOADB(bA, 0)
    #pragma unroll 1
    for (int t = 0; t < 32; t += 2) {
        K23_LOADB(bB, t + 1)          // in flight across BODY(t)
        K23_BODY(t, bA)
        if (t + 2 < 32) { K23_LOADB(bA, t + 2) }  // in flight across BODY(t+1)
        K23_BODY(t + 1, bB)
    }
#undef K23_LOADB
#undef K23_BODY

    // merged epilogue: fold wave-pair (wn, wn+64) partials in LDS, then
    // one coalesced atomicAdd set. As (16KB) aliased as 64x64 f32 merge buf.
    __syncthreads();                       // all waves done with As/yT
    float* mg = (float*)As;
    const int fb = (wn & 32);
    if (wave < 2) {
        #pragma unroll
        for (int mt = 0; mt < 4; ++mt)
            #pragma unroll
            for (int r = 0; r < 4; ++r)
                #pragma unroll
                for (int nt = 0; nt < 2; ++nt)
                    mg[(mt * 16 + quad * 4 + r) * 64 + fb + nt * 16 + lr] = msum[mt][nt][r];
    }
    __syncthreads();
    if (wave >= 2) {
        #pragma unroll
        for (int mt = 0; mt < 4; ++mt)
            #pragma unroll
            for (int r = 0; r < 4; ++r)
                #pragma unroll
                for (int nt = 0; nt < 2; ++nt)
                    mg[(mt * 16 + quad * 4 + r) * 64 + fb + nt * 16 + lr] += msum[mt][nt][r];
    }
    __syncthreads();
    #pragma unroll
    for (int i = 0; i < 16; ++i) {
        const int o = i * 256 + tid;
        const int row = o >> 6, col = o & 63;
        atomicAdd(&agg[(size_t)sdx[row] * 64 + col], mg[o]);
    }
}

// GRU v5: MFMA gate GEMMs + agg zeroed in-place after read (each thread
// zeroes exactly the 16 floats it read; grid covers all nodes) -> the 3
// in-loop 16MB memset dispatches disappear.
__global__ __launch_bounds__(256) void k4_gru(float* __restrict__ agg,
                                              const float* __restrict__ counts,
                                              const float* __restrict__ cbias,
                                              const __hip_bfloat16* __restrict__ gwp,
                                              const float* __restrict__ b_ih,
                                              const float* __restrict__ b_hh,
                                              float* __restrict__ out) {
    const int wv = threadIdx.x >> 6, lane = threadIdx.x & 63;
    const int lr = lane & 15, quad = lane >> 4;
    const int wnb0 = blockIdx.x * 64 + wv * 16;
    const int node = wnb0 + lr;

    const float rcnt = 1.0f / fmaxf(counts[node], 1.0f);
    float* ap = agg + (size_t)node * 64;
    const float* hp = out + (size_t)node * 64;
    short8 am[2], ah[2];
    #pragma unroll
    for (int kk = 0; kk < 2; ++kk) {
        const int k0 = kk * 32 + quad * 8;
        #pragma unroll
        for (int j = 0; j < 8; ++j) {
            const float mv = fmaxf(ap[k0 + j] * rcnt + cbias[k0 + j], 0.0f);
            const __hip_bfloat16 mb = __float2bfloat16(mv);
            am[kk][j] = *(const short*)&mb;
            const __hip_bfloat16 hb = __float2bfloat16(hp[k0 + j]);
            ah[kk][j] = *(const short*)&hb;
        }
    }
    // zero agg for the next NNConv iteration (replaces memset dispatch)
    {
        const float4 z = {0.0f, 0.0f, 0.0f, 0.0f};
        #pragma unroll
        for (int kk = 0; kk < 2; ++kk) {
            const int k0 = kk * 32 + quad * 8;
            *(float4*)(ap + k0) = z;
            *(float4*)(ap + k0 + 4) = z;
        }
    }

    floatx4 ai[12] = {}, ahh[12] = {};
    #pragma unroll
    for (int nb = 0; nb < 12; ++nb) {
        #pragma unroll
        for (int kk = 0; kk < 2; ++kk) {
            #pragma unroll
            for (int part = 0; part < 2; ++part) {
                const short8 bi = *(const short8*)(gwp + (size_t)(((0 * 12 + nb) * 2 + kk) * 2 + part) * 512 + lane * 8);
                ai[nb] = __builtin_amdgcn_mfma_f32_16x16x32_bf16(am[kk], bi, ai[nb], 0, 0, 0);
                const short8 bh = *(const short8*)(gwp + (size_t)(((1 * 12 + nb) * 2 + kk) * 2 + part) * 512 + lane * 8);
                ahh[nb] = __builtin_amdgcn_mfma_f32_16x16x32_bf16(ah[kk], bh, ahh[nb], 0, 0, 0);
            }
        }
    }

    #pragma unroll
    for (int f = 0; f < 4; ++f) {
        const int d = f * 16 + lr;
        const float bir = b_ih[d],       bhr = b_hh[d];
        const float biz = b_ih[64 + d],  bhz = b_hh[64 + d];
        const float bin = b_ih[128 + d], bhn = b_hh[128 + d];
        #pragma unroll
        for (int r = 0; r < 4; ++r) {
            const int row = wnb0 + quad * 4 + r;
            const float rr = sigm(ai[f][r] + bir + ahh[f][r] + bhr);
            const float zz = sigm(ai[f + 4][r] + biz + ahh[f + 4][r] + bhz);
            const float nn = tanhf(ai[f + 8][r] + bin + rr * (ahh[f + 8][r] + bhn));
            const float hd = out[(size_t)row * 64 + d];
            out[(size_t)row * 64 + d] = (1.0f - zz) * nn + zz * hd;
        }
    }
}

// FUSED Set2Set: all 3 processing steps in ONE launch.
__global__ __launch_bounds__(256) void k5_fused(float* __restrict__ qstar,
                                                const float* __restrict__ w_ih,
                                                const float* __restrict__ w_hh,
                                                const float* __restrict__ b_ih,
                                                const float* __restrict__ b_hh,
                                                const float* __restrict__ out,
                                                const int* __restrict__ rowptr) {
    const int g = blockIdx.x;
    const int j = threadIdx.x;
    __shared__ float qs[128], hv[64], gates[256];
    __shared__ float smw[4], sSw[4], srw[4][64];
    if (j < 128) qs[j] = 0.0f;
    if (j < 64) hv[j] = 0.0f;
    float creg = 0.0f;               // cs state (threads j<64)
    const int wv = j >> 6, lane = j & 63;
    const int start = rowptr[g], end = rowptr[g + 1];
    const float bsum = b_ih[j] + b_hh[j];

    for (int step = 0; step < 3; ++step) {
        __syncthreads();             // qs/hv (and smw/srw reuse) ready
        float acc = bsum;
        for (int k4 = 0; k4 < 128; k4 += 4) {
            float4 v = *(const float4*)(w_ih + (size_t)j * 128 + k4);
            const float* pv = (const float*)&v;
            #pragma unroll
            for (int t = 0; t < 4; ++t) acc += qs[k4 + t] * pv[t];
        }
        for (int k4 = 0; k4 < 64; k4 += 4) {
            float4 v = *(const float4*)(w_hh + (size_t)j * 64 + k4);
            const float* pv = (const float*)&v;
            #pragma unroll
            for (int t = 0; t < 4; ++t) acc += hv[k4 + t] * pv[t];
        }
        gates[j] = acc;
        __syncthreads();
        if (j < 64) {
            const float ig = sigm(gates[j]);
            const float fg = sigm(gates[64 + j]);
            const float gg = tanhf(gates[128 + j]);
            const float og = sigm(gates[192 + j]);
            creg = fg * creg + ig * gg;
            const float h = og * tanhf(creg);
            hv[j] = h;
            qs[j] = h;
        }
        __syncthreads();
        // attention: wave wv handles nodes start+wv, start+wv+4, ...
        const float q = hv[lane];
        float m = -3.4e38f, S = 0.0f, racc = 0.0f;
        for (int n = start + wv; n < end; n += 4) {
            const float ov = out[(size_t)n * 64 + lane];
            float p = ov * q;
            #pragma unroll
            for (int off = 1; off < 64; off <<= 1) p += __shfl_xor(p, off);
            if (p > m) {
                const float sc = __expf(m - p);
                S = S * sc + 1.0f;
                racc = racc * sc + ov;
                m = p;
            } else {
                const float w = __expf(p - m);
                S += w;
                racc += w * ov;
            }
        }
        if (lane == 0) { smw[wv] = m; sSw[wv] = S; }
        srw[wv][lane] = racc;
        __syncthreads();
        if (wv == 0) {
            const float mstar = fmaxf(fmaxf(smw[0], smw[1]), fmaxf(smw[2], smw[3]));
            float Ssum = 0.0f, rsum = 0.0f;
            #pragma unroll
            for (int i = 0; i < 4; ++i) {
                const float sc = __expf(smw[i] - mstar);   // empty wave: exp(-huge)=0
                Ssum += sSw[i] * sc;
                rsum += srw[i][lane] * sc;
            }
            qs[64 + lane] = rsum / (Ssum + 1e-16f);
        }
    }
    __syncthreads();
    if (j < 128) qstar[(size_t)g * 128 + j] = qs[j];
}

__global__ void k_out(const float* __restrict__ qstar, const float* __restrict__ outb,
                      float* __restrict__ dst, int nq, int nfeat, int out_n) {
    int i = blockIdx.x * 256 + threadIdx.x;
    if (i >= out_n) return;
    float v = 0.0f;
    if (i < nq) v = qstar[i];
    else if (i - nq < nfeat) v = outb[i - nq];
    dst[i] = v;
}

extern "C" void kernel_launch(void* const* d_in, const int* in_sizes, int n_in,
                              void* d_out, int out_size, void* d_ws, size_t ws_size,
                              hipStream_t stream) {
    constexpr int N = GN, E = GE, B = GB;

    char* ws = (char*)d_ws;
    size_t off = 0;
    auto alloc = [&](size_t bytes) { size_t o = off; off = (off + bytes + 255) & ~(size_t)255; return o; };

    int*   fl     = (int*)  (ws + alloc(19 * 4));
    int*   flagE  = (int*)  (ws + alloc(256));
    int*   flagG  = (int*)  (ws + alloc(256));
    float* counts = (float*)(ws + alloc((size_t)N * 4));
    int*   rowptr = (int*)  (ws + alloc((size_t)(B + 1) * 4));
    float* outbuf = (float*)(ws + alloc((size_t)N * 64 * 4));
    float* agg    = (float*)(ws + alloc((size_t)N * 64 * 4));
    float* qstar  = (float*)(ws + alloc((size_t)B * 128 * 4));
    __hip_bfloat16* h1P = (__hip_bfloat16*)(ws + alloc((size_t)E * 128 * 2));
    __hip_bfloat16* w2P = (__hip_bfloat16*)(ws + alloc((size_t)4096 * 128 * 2));
    __hip_bfloat16* gwp = (__hip_bfloat16*)(ws + alloc((size_t)2 * 12 * 2 * 2 * 512 * 2));

    const int fidx[15]  = {4, 5, 6, 7, 8, 9, 10, 11, 12, 13, 14, 15, 16, 17, 18};
    const int fsize[15] = {75 * 64, 64, 16 * 128, 128, 128 * 4096, 4096, 64,
                           192 * 64, 192 * 64, 192, 192, 256 * 128, 256 * 64, 256, 256};
    float* F[19] = {};
    for (int t = 0; t < 15; ++t) F[fidx[t]] = (float*)(ws + alloc((size_t)fsize[t] * 4));

    DetectArgs da;
    da.src[0] = d_in[0]; da.nhalf[0] = N * 75; da.fi[0] = 0;
    da.src[1] = d_in[1]; da.nhalf[1] = E * 16; da.fi[1] = 1;
    for (int t = 0; t < 15; ++t) { da.src[2 + t] = d_in[fidx[t]]; da.nhalf[2 + t] = fsize[t]; da.fi[2 + t] = fidx[t]; }
    k_detect<<<19, 256, 0, stream>>>(da, (const unsigned int*)d_in[2],
                                     (const unsigned int*)d_in[3], fl, flagE, flagG);

    // cvt list: 14 tensors (w2 -> F[8] dropped; consumed via k_t2 directly)
    const int cidx[14]  = {4, 5, 6, 7, 9, 10, 11, 12, 13, 14, 15, 16, 17, 18};
    const int csize[14] = {75 * 64, 64, 16 * 128, 128, 4096, 64,
                           192 * 64, 192 * 64, 192, 192, 256 * 128, 256 * 64, 256, 256};
    CvtArgs ca;
    int pre = 0;
    for (int t = 0; t < 14; ++t) {
        ca.src[t] = d_in[cidx[t]]; ca.dst[t] = F[cidx[t]]; ca.n[t] = csize[t]; ca.fi[t] = cidx[t];
        ca.pre[t] = pre; pre += (csize[t] + 255) / 256;
    }
    ca.src[14] = d_in[4]; ca.dst[14] = F[4]; ca.n[14] = 0; ca.fi[14] = 4;
    ca.pre[14] = pre; ca.pre[15] = pre;
    k_cvt_all<<<pre, 256, 0, stream>>>(ca, fl);
    k_t2<<<256, 256, 0, stream>>>(d_in[8], w2P, fl + 8);
    k_gpack2<<<12, 256, 0, stream>>>(F[11], F[12], gwp);

    hipMemsetAsync(counts, 0, (size_t)N * 4, stream);
    hipMemsetAsync(qstar, 0, (size_t)B * 128 * 4, stream);
    hipMemsetAsync(agg, 0, (size_t)N * 64 * 4, stream);

    k_cnt_rp<<<512 + (B + 1 + 255) / 256, 256, 0, stream>>>(d_in[2], d_in[3], flagE, flagG,
                                                            counts, rowptr);
    k_lin0<<<N / 16, 256, 0, stream>>>(d_in[0], F[4], F[5], outbuf, fl + 0);
    k1_h1<<<E / 16, 256, 0, stream>>>(d_in[1], F[6], F[7], h1P, fl + 1);

    for (int it = 0; it < 3; ++it) {
        k23_fused<<<E / 64, 256, 0, stream>>>(h1P, w2P, F[9], outbuf, d_in[2], flagE, agg);
        k4_gru<<<N / 64, 256, 0, stream>>>(agg, counts, F[10], gwp, F[13], F[14], outbuf);
    }
    k5_fused<<<B, 256, 0, stream>>>(qstar, F[15], F[16], F[17], F[18], outbuf, rowptr);
    k_out<<<(out_size + 255) / 256, 256, 0, stream>>>(qstar, outbuf, (float*)d_out,
                                                      B * 128, N * 64, out_size);
}